// Round 9
// baseline (240.631 us; speedup 1.0000x reference)
//
#include <hip/hip_runtime.h>

// GraphNN collapsed to exact affine form:
//   out = (x @ Mo + co) / n_out; norms from G = x^T x, s = colsum(x):
//   n^2 = sum_{w,w'} G[w][w']*H[w][w'] + c-terms,  H = Tt Tt^T.
// Round 9: (a) kG stores an L3-resident bf16 copy of x that kApply reads
// (HBM 201->168 MB across the pair); (b) kNorm fused into kChainB via
// last-block-done (threadfence + atomic ticket, counter memset per call).
// 5 dispatches: kG -> kGred -> kChainA -> kChainB(+norm) -> kApply.

#define BF 262144.0f
#define SLOT 4608           // 64*72 u16 per matrix slot

// ws float offsets
#define OFF_G   0
#define OFF_S   4096
#define OFF_P2  8192        // 16 slots * 4096
#define OFF_C2  73728       // 1024
#define OFF_P4  74752       // 4 slots * 4096
#define OFF_C4  91136       // 256
#define OFF_MO  91392       // 4096
#define OFF_CO  95488       // 64
#define OFF_CTR 95552       // 1 int
#define OFF_X16 98304       // bf16 x copy: 16.78M u16 = 33.6 MB

typedef __attribute__((ext_vector_type(8))) short bf16x8;   // 8 bf16 = 4 VGPRs
typedef __attribute__((ext_vector_type(4))) float f32x4;
typedef __attribute__((ext_vector_type(4))) unsigned short u16x4;

__device__ __forceinline__ unsigned short f2bf(float f) {
  unsigned u = __builtin_bit_cast(unsigned, f);
  u += 0x7FFF + ((u >> 16) & 1);          // round-to-nearest-even
  return (unsigned short)(u >> 16);
}
__device__ __forceinline__ float bf2f(unsigned short h) {
  unsigned u = ((unsigned)h) << 16;
  return __builtin_bit_cast(float, u);
}

__device__ __forceinline__ bf16x8 cvt8(f32x4 a, f32x4 b, float s) {
  bf16x8 t;
#pragma unroll
  for (int j = 0; j < 4; j++) {
    t[j]     = (short)f2bf(a[j] * s);
    t[j + 4] = (short)f2bf(b[j] * s);
  }
  return t;
}

// split 8 floats (scaled) into hi/lo bf16x8
__device__ __forceinline__ void split8(f32x4 a, f32x4 b, float sc,
                                       bf16x8& hi, bf16x8& lo) {
#pragma unroll
  for (int j = 0; j < 4; j++) {
    float v = a[j] * sc;
    unsigned short h = f2bf(v);
    hi[j] = (short)h; lo[j] = (short)f2bf(v - bf2f(h));
    v = b[j] * sc;
    h = f2bf(v);
    hi[j + 4] = (short)h; lo[j + 4] = (short)f2bf(v - bf2f(h));
  }
}

// q MFMA part: sum_{w,w'} G[w][w'] * (Tt Tt^T)[w][w'] for one T-slot
__device__ __forceinline__ float qpart(const unsigned short* th,
                                       const unsigned short* tl,
                                       int it, int col, int quad,
                                       const float Greg[4][4]) {
  f32x4 dq[4];
#pragma unroll
  for (int ut = 0; ut < 4; ut++) dq[ut] = (f32x4){0.f, 0.f, 0.f, 0.f};
#pragma unroll
  for (int ks = 0; ks < 2; ks++) {
    const bf16x8 ah = *(const bf16x8*)&th[(it * 16 + col) * 72 + ks * 32 + quad * 8];
    const bf16x8 al = *(const bf16x8*)&tl[(it * 16 + col) * 72 + ks * 32 + quad * 8];
#pragma unroll
    for (int ut = 0; ut < 4; ut++) {
      const bf16x8 bh = *(const bf16x8*)&th[(ut * 16 + col) * 72 + ks * 32 + quad * 8];
      const bf16x8 bl = *(const bf16x8*)&tl[(ut * 16 + col) * 72 + ks * 32 + quad * 8];
      dq[ut] = __builtin_amdgcn_mfma_f32_16x16x32_bf16(ah, bh, dq[ut], 0, 0, 0);
      dq[ut] = __builtin_amdgcn_mfma_f32_16x16x32_bf16(ah, bl, dq[ut], 0, 0, 0);
      dq[ut] = __builtin_amdgcn_mfma_f32_16x16x32_bf16(al, bh, dq[ut], 0, 0, 0);
    }
  }
  float qp = 0.f;
#pragma unroll
  for (int ut = 0; ut < 4; ut++)
#pragma unroll
    for (int r = 0; r < 4; r++) qp += dq[ut][r] * Greg[ut][r];
  return qp;
}

// block reduction of qp -> qvv[idx] = 1/sqrt(sum); uniform control flow
__device__ __forceinline__ void blkred(float qp, float* red4, float* qvv,
                                       int idx, int tid, int lane, int it) {
#pragma unroll
  for (int off = 32; off; off >>= 1) qp += __shfl_down(qp, off, 64);
  if (lane == 0) red4[it] = qp;
  __syncthreads();
  if (tid == 0) qvv[idx] = 1.0f / sqrtf(red4[0] + red4[1] + red4[2] + red4[3]);
  __syncthreads();
}

// ---------- kG: partial G = x^T x (bf16 MFMA) + colsum + bf16-x copy --------
__global__ __launch_bounds__(256) void kG(const float* __restrict__ x,
                                          float* __restrict__ Gpart,
                                          unsigned short* __restrict__ x16) {
  __shared__ __align__(16) unsigned short xts[4][4][16][8];
  __shared__ float sred[256][4];
  const int tid = threadIdx.x;
  const int lane = tid & 63, mt = tid >> 6;
  const int col = lane & 15, q = lane >> 4;
  const int row0 = tid >> 4;
  const int cf0  = (tid & 15) * 4;

  f32x4 acc[4];
#pragma unroll
  for (int nt = 0; nt < 4; nt++) acc[nt] = (f32x4){0.f, 0.f, 0.f, 0.f};
  float s0 = 0.f, s1 = 0.f, s2 = 0.f, s3 = 0.f;

  const long brow = (long)blockIdx.x * 512;
  const float* bx = x + brow * 64;
  f32x4 r0 = *(const f32x4*)(bx + tid * 4);
  f32x4 r1 = *(const f32x4*)(bx + 1024 + tid * 4);

  for (int c = 0; c < 16; c++) {
    __syncthreads();
    s0 += r0[0] + r1[0]; s1 += r0[1] + r1[1];
    s2 += r0[2] + r1[2]; s3 += r0[3] + r1[3];
    u16x4 h0, h1;
#pragma unroll
    for (int j = 0; j < 4; j++) {
      const int cf = cf0 + j;
      const unsigned short b0 = f2bf(r0[j]);
      const unsigned short b1 = f2bf(r1[j]);
      h0[j] = b0; h1[j] = b1;
      xts[cf >> 4][row0 >> 3][cf & 15][row0 & 7]        = b0;
      xts[cf >> 4][2 + (row0 >> 3)][cf & 15][row0 & 7]  = b1;
    }
    *(u16x4*)(x16 + (brow + c * 32 + row0) * 64 + cf0)      = h0;
    *(u16x4*)(x16 + (brow + c * 32 + 16 + row0) * 64 + cf0) = h1;
    f32x4 r0n = r0, r1n = r1;
    if (c < 15) {
      r0n = *(const f32x4*)(bx + (c + 1) * 2048 + tid * 4);
      r1n = *(const f32x4*)(bx + (c + 1) * 2048 + 1024 + tid * 4);
    }
    __syncthreads();
    const bf16x8 af = *(const bf16x8*)xts[mt][q][col];
#pragma unroll
    for (int nt = 0; nt < 4; nt++) {
      const bf16x8 bfr = *(const bf16x8*)xts[nt][q][col];
      acc[nt] = __builtin_amdgcn_mfma_f32_16x16x32_bf16(af, bfr, acc[nt], 0, 0, 0);
    }
    r0 = r0n; r1 = r1n;
  }

  float* myp = Gpart + (long)blockIdx.x * 4160;
#pragma unroll
  for (int nt = 0; nt < 4; nt++)
#pragma unroll
    for (int r = 0; r < 4; r++)
      myp[(mt * 16 + q * 4 + r) * 64 + nt * 16 + col] = acc[nt][r];

  sred[tid][0] = s0; sred[tid][1] = s1; sred[tid][2] = s2; sred[tid][3] = s3;
  __syncthreads();
  if (tid < 64) {
    float t = 0.f;
#pragma unroll
    for (int k2 = 0; k2 < 16; k2++) t += sred[(tid >> 2) + 16 * k2][tid & 3];
    myp[4096 + tid] = t;
  }
}

// ---------- kGred: reduce 512 partials -> G, s (coalesced) ------------------
__global__ __launch_bounds__(256) void kGred(const float* __restrict__ Gpart,
                                             float* __restrict__ G,
                                             float* __restrict__ s) {
  __shared__ float red[4][64];
  const int tid = threadIdx.x;
  const int e = blockIdx.x * 64 + (tid & 63);
  const int quarter = tid >> 6;
  float acc = 0.f;
#pragma unroll 4
  for (int j = 0; j < 128; j++)
    acc += Gpart[(long)(quarter * 128 + j) * 4160 + e];
  red[quarter][tid & 63] = acc;
  __syncthreads();
  if (tid < 64) {
    const float t = red[0][tid] + red[1][tid] + red[2][tid] + red[3][tid];
    const int ee = blockIdx.x * 64 + tid;
    if (ee < 4096) G[ee] = t;
    else           s[ee - 4096] = t;
  }
}

// ---------- kChainA: levels 1+2. Block (p2,k2). ----------------------------
__global__ __launch_bounds__(256) void kChainA(
    const float* __restrict__ Win, const float* __restrict__ bin,
    const float* __restrict__ Wm0, const float* __restrict__ bm0,
    const float* __restrict__ Wm1, const float* __restrict__ bm1,
    const float* __restrict__ G, const float* __restrict__ s,
    float* __restrict__ Pout, float* __restrict__ cpout) {
  extern __shared__ __align__(16) char smem[];
  unsigned short* Tth = (unsigned short*)smem;
  unsigned short* Ttl = Tth + 4 * SLOT;
  float* cAv  = (float*)(Ttl + 4 * SLOT);   // 256
  float* cBv  = cAv + 256;                  // 64
  float* slv  = cBv + 64;                   // 64
  float* red4 = slv + 64;                   // 4
  float* qvv  = red4 + 4;                   // 8

  const int tid = threadIdx.x;
  const int p2 = blockIdx.x >> 2, k2 = blockIdx.x & 3;
  const int lane = tid & 63, it = tid >> 6;
  const int col = lane & 15, quad = lane >> 4;

  float Greg[4][4];
#pragma unroll
  for (int ut = 0; ut < 4; ut++)
#pragma unroll
    for (int r = 0; r < 4; r++)
      Greg[ut][r] = G[(it * 16 + quad * 4 + r) * 64 + ut * 16 + col];
  if (tid < 64) slv[tid] = s[tid];
  if (tid < 256) cAv[tid] = bin[tid];      // c1[p][v], contiguous

  // build T1 slots (split+transpose straight from global)
  {
    const int tc = tid >> 2, rb = (tid & 3) * 16;
#pragma unroll
    for (int p = 0; p < 4; p++)
#pragma unroll
      for (int j = 0; j < 16; j++) {
        const float tv = Win[p * 4096 + (rb + j) * 64 + tc];
        const unsigned short h = f2bf(tv);
        Tth[p * SLOT + tc * 72 + rb + j] = h;
        Ttl[p * SLOT + tc * 72 + rb + j] = f2bf(tv - bf2f(h));
      }
  }
  __syncthreads();

  // q1_p -> qvv[0..3]
#pragma unroll
  for (int p = 0; p < 4; p++) {
    float qp = qpart(Tth + p * SLOT, Ttl + p * SLOT, it, col, quad, Greg);
    if (tid < 64) {
      float sd = 0.f;
      for (int w = 0; w < 64; w++)
        sd += slv[w] * (bf2f(Tth[p * SLOT + w * 72 + tid]) +
                        bf2f(Ttl[p * SLOT + w * 72 + tid]));
      const float c = cAv[p * 64 + tid];
      qp += c * (2.f * sd + BF * c);
    }
    blkred(qp, red4, qvv, p, tid, lane, it);
  }

  // compose T2_p2 = sum_p inv1_p * (Wm0_{p,p2} @ T1_p); c2 in parallel
  f32x4 dc[4];
#pragma unroll
  for (int nt = 0; nt < 4; nt++) dc[nt] = (f32x4){0.f, 0.f, 0.f, 0.f};
  float c2acc = 0.f;

  const int arow = it * 16 + col;
  f32x4 wr[4];
  {
    const float* wbase = Wm0 + (long)((0 * 4 + p2) * 64 + arow) * 64;
    wr[0] = *(const f32x4*)(wbase + quad * 8);
    wr[1] = *(const f32x4*)(wbase + quad * 8 + 4);
    wr[2] = *(const f32x4*)(wbase + 32 + quad * 8);
    wr[3] = *(const f32x4*)(wbase + 36 + quad * 8);
  }
#pragma unroll
  for (int p = 0; p < 4; p++) {
    const float inv = qvv[p];
    bf16x8 awh0, awl0, awh1, awl1;
    split8(wr[0], wr[1], inv, awh0, awl0);
    split8(wr[2], wr[3], inv, awh1, awl1);
    if (p < 3) {
      const float* wbase = Wm0 + (long)(((p + 1) * 4 + p2) * 64 + arow) * 64;
      wr[0] = *(const f32x4*)(wbase + quad * 8);
      wr[1] = *(const f32x4*)(wbase + quad * 8 + 4);
      wr[2] = *(const f32x4*)(wbase + 32 + quad * 8);
      wr[3] = *(const f32x4*)(wbase + 36 + quad * 8);
    }
#pragma unroll
    for (int nt = 0; nt < 4; nt++) {
      const bf16x8 bh0 = *(const bf16x8*)&Tth[p * SLOT + (nt * 16 + col) * 72 + quad * 8];
      const bf16x8 bl0 = *(const bf16x8*)&Ttl[p * SLOT + (nt * 16 + col) * 72 + quad * 8];
      dc[nt] = __builtin_amdgcn_mfma_f32_16x16x32_bf16(awh0, bh0, dc[nt], 0, 0, 0);
      dc[nt] = __builtin_amdgcn_mfma_f32_16x16x32_bf16(awh0, bl0, dc[nt], 0, 0, 0);
      dc[nt] = __builtin_amdgcn_mfma_f32_16x16x32_bf16(awl0, bh0, dc[nt], 0, 0, 0);
      const bf16x8 bh1 = *(const bf16x8*)&Tth[p * SLOT + (nt * 16 + col) * 72 + 32 + quad * 8];
      const bf16x8 bl1 = *(const bf16x8*)&Ttl[p * SLOT + (nt * 16 + col) * 72 + 32 + quad * 8];
      dc[nt] = __builtin_amdgcn_mfma_f32_16x16x32_bf16(awh1, bh1, dc[nt], 0, 0, 0);
      dc[nt] = __builtin_amdgcn_mfma_f32_16x16x32_bf16(awh1, bl1, dc[nt], 0, 0, 0);
      dc[nt] = __builtin_amdgcn_mfma_f32_16x16x32_bf16(awl1, bh1, dc[nt], 0, 0, 0);
    }
    if (tid < 64) {
      const float* wrow = Wm0 + (long)((p * 4 + p2) * 64 + tid) * 64;
      float pc = 0.f;
#pragma unroll
      for (int u4 = 0; u4 < 16; u4++) {
        const f32x4 wv = *(const f32x4*)(wrow + u4 * 4);
        pc += wv[0] * cAv[p * 64 + u4 * 4]     + wv[1] * cAv[p * 64 + u4 * 4 + 1] +
              wv[2] * cAv[p * 64 + u4 * 4 + 2] + wv[3] * cAv[p * 64 + u4 * 4 + 3];
      }
      c2acc += inv * pc + bm0[(p * 4 + p2) * 64 + tid];
    }
  }
  __syncthreads();    // all slot reads done before overwriting slot 0

  // write T2 (split+transposed) into slot 0; publish c2
#pragma unroll
  for (int nt = 0; nt < 4; nt++)
#pragma unroll
    for (int r = 0; r < 4; r++) {
      const float val = dc[nt][r];
      const unsigned short h = f2bf(val);
      const int w_ = nt * 16 + col, v_ = it * 16 + quad * 4 + r;
      Tth[w_ * 72 + v_] = h;
      Ttl[w_ * 72 + v_] = f2bf(val - bf2f(h));
    }
  if (tid < 64) cBv[tid] = c2acc;
  __syncthreads();

  // q2 -> qvv[4]
  {
    float qp = qpart(Tth, Ttl, it, col, quad, Greg);
    if (tid < 64) {
      float sd = 0.f;
      for (int w = 0; w < 64; w++)
        sd += slv[w] * (bf2f(Tth[w * 72 + tid]) + bf2f(Ttl[w * 72 + tid]));
      const float c = cBv[tid];
      qp += c * (2.f * sd + BF * c);
    }
    blkred(qp, red4, qvv, 4, tid, lane, it);
  }
  const float inv2 = qvv[4];

  // output: P2[p2][k2] = inv2 * (Wm1_{p2,k2} @ T2)
  {
    f32x4 dcO[4];
#pragma unroll
    for (int nt = 0; nt < 4; nt++) dcO[nt] = (f32x4){0.f, 0.f, 0.f, 0.f};
    const float* wbase = Wm1 + (long)((p2 * 4 + k2) * 64 + arow) * 64;
    const f32x4 w0 = *(const f32x4*)(wbase + quad * 8);
    const f32x4 w1 = *(const f32x4*)(wbase + quad * 8 + 4);
    const f32x4 w2 = *(const f32x4*)(wbase + 32 + quad * 8);
    const f32x4 w3 = *(const f32x4*)(wbase + 36 + quad * 8);
    bf16x8 awh0, awl0, awh1, awl1;
    split8(w0, w1, inv2, awh0, awl0);
    split8(w2, w3, inv2, awh1, awl1);
#pragma unroll
    for (int nt = 0; nt < 4; nt++) {
      const bf16x8 bh0 = *(const bf16x8*)&Tth[(nt * 16 + col) * 72 + quad * 8];
      const bf16x8 bl0 = *(const bf16x8*)&Ttl[(nt * 16 + col) * 72 + quad * 8];
      dcO[nt] = __builtin_amdgcn_mfma_f32_16x16x32_bf16(awh0, bh0, dcO[nt], 0, 0, 0);
      dcO[nt] = __builtin_amdgcn_mfma_f32_16x16x32_bf16(awh0, bl0, dcO[nt], 0, 0, 0);
      dcO[nt] = __builtin_amdgcn_mfma_f32_16x16x32_bf16(awl0, bh0, dcO[nt], 0, 0, 0);
      const bf16x8 bh1 = *(const bf16x8*)&Tth[(nt * 16 + col) * 72 + 32 + quad * 8];
      const bf16x8 bl1 = *(const bf16x8*)&Ttl[(nt * 16 + col) * 72 + 32 + quad * 8];
      dcO[nt] = __builtin_amdgcn_mfma_f32_16x16x32_bf16(awh1, bh1, dcO[nt], 0, 0, 0);
      dcO[nt] = __builtin_amdgcn_mfma_f32_16x16x32_bf16(awh1, bl1, dcO[nt], 0, 0, 0);
      dcO[nt] = __builtin_amdgcn_mfma_f32_16x16x32_bf16(awl1, bh1, dcO[nt], 0, 0, 0);
    }
    float* po = Pout + (long)(p2 * 4 + k2) * 4096;
#pragma unroll
    for (int nt = 0; nt < 4; nt++)
#pragma unroll
      for (int r = 0; r < 4; r++)
        po[(it * 16 + quad * 4 + r) * 64 + nt * 16 + col] = dcO[nt][r];
    if (tid < 64) {
      const float* wrow = Wm1 + (long)((p2 * 4 + k2) * 64 + tid) * 64;
      float pc = 0.f;
#pragma unroll
      for (int u4 = 0; u4 < 16; u4++) {
        const f32x4 wv = *(const f32x4*)(wrow + u4 * 4);
        pc += wv[0] * cBv[u4 * 4]     + wv[1] * cBv[u4 * 4 + 1] +
              wv[2] * cBv[u4 * 4 + 2] + wv[3] * cBv[u4 * 4 + 3];
      }
      cpout[(p2 * 4 + k2) * 64 + tid] = inv2 * pc + bm1[(p2 * 4 + k2) * 64 + tid];
    }
  }
}

// ---------- kChainB: levels 3+4 + fused final norm (last-block-done) --------
__global__ __launch_bounds__(256) void kChainB(
    const float* __restrict__ Pin, const float* __restrict__ cpin,
    const float* __restrict__ Wm2, const float* __restrict__ bm2,
    const float* __restrict__ Wout, const float* __restrict__ bout,
    const float* __restrict__ G, const float* __restrict__ s,
    float* __restrict__ Pout, float* __restrict__ cpout,
    float* __restrict__ MoS, float* __restrict__ coS,
    int* __restrict__ ctr) {
  extern __shared__ __align__(16) char smem[];
  unsigned short* Tth = (unsigned short*)smem;
  unsigned short* Ttl = Tth + 4 * SLOT;
  float* cAv  = (float*)(Ttl + 4 * SLOT);   // 256  (c3[k][v])
  float* cBv  = cAv + 256;                  // 64   (c4)
  float* slv  = cBv + 64;                   // 64
  float* red4 = slv + 64;                   // 4
  float* qvv  = red4 + 4;                   // 8
  __shared__ int isLast;

  const int tid = threadIdx.x;
  const int kp = blockIdx.x;                // k' (output node of level 4)
  const int lane = tid & 63, it = tid >> 6;
  const int col = lane & 15, quad = lane >> 4;

  float Greg[4][4];
#pragma unroll
  for (int ut = 0; ut < 4; ut++)
#pragma unroll
    for (int r = 0; r < 4; r++)
      Greg[ut][r] = G[(it * 16 + quad * 4 + r) * 64 + ut * 16 + col];
  if (tid < 64) slv[tid] = s[tid];
  if (tid < 256) {
    const int k = tid >> 6, v = tid & 63;
    cAv[tid] = cpin[(0 * 4 + k) * 64 + v] + cpin[(1 * 4 + k) * 64 + v] +
               cpin[(2 * 4 + k) * 64 + v] + cpin[(3 * 4 + k) * 64 + v];
  }

  // build T3 slots: T3_k = sum_p P2[p][k]
  {
    const int tc = tid >> 2, rb = (tid & 3) * 16;
#pragma unroll
    for (int k = 0; k < 4; k++)
#pragma unroll
      for (int j = 0; j < 16; j++) {
        const int off = (rb + j) * 64 + tc;
        const float tv = Pin[(0 * 4 + k) * 4096 + off] + Pin[(1 * 4 + k) * 4096 + off] +
                         Pin[(2 * 4 + k) * 4096 + off] + Pin[(3 * 4 + k) * 4096 + off];
        const unsigned short h = f2bf(tv);
        Tth[k * SLOT + tc * 72 + rb + j] = h;
        Ttl[k * SLOT + tc * 72 + rb + j] = f2bf(tv - bf2f(h));
      }
  }
  __syncthreads();

  // q3_k -> qvv[0..3]
#pragma unroll
  for (int k = 0; k < 4; k++) {
    float qp = qpart(Tth + k * SLOT, Ttl + k * SLOT, it, col, quad, Greg);
    if (tid < 64) {
      float sd = 0.f;
      for (int w = 0; w < 64; w++)
        sd += slv[w] * (bf2f(Tth[k * SLOT + w * 72 + tid]) +
                        bf2f(Ttl[k * SLOT + w * 72 + tid]));
      const float c = cAv[k * 64 + tid];
      qp += c * (2.f * sd + BF * c);
    }
    blkred(qp, red4, qvv, k, tid, lane, it);
  }

  // compose T4_{k'} = sum_k inv3_k * (Wm2_{k,k'} @ T3_k); c4 in parallel
  f32x4 dc[4];
#pragma unroll
  for (int nt = 0; nt < 4; nt++) dc[nt] = (f32x4){0.f, 0.f, 0.f, 0.f};
  float c4acc = 0.f;

  const int arow = it * 16 + col;
  f32x4 wr[4];
  {
    const float* wbase = Wm2 + (long)((0 * 4 + kp) * 64 + arow) * 64;
    wr[0] = *(const f32x4*)(wbase + quad * 8);
    wr[1] = *(const f32x4*)(wbase + quad * 8 + 4);
    wr[2] = *(const f32x4*)(wbase + 32 + quad * 8);
    wr[3] = *(const f32x4*)(wbase + 36 + quad * 8);
  }
#pragma unroll
  for (int k = 0; k < 4; k++) {
    const float inv = qvv[k];
    bf16x8 awh0, awl0, awh1, awl1;
    split8(wr[0], wr[1], inv, awh0, awl0);
    split8(wr[2], wr[3], inv, awh1, awl1);
    if (k < 3) {
      const float* wbase = Wm2 + (long)(((k + 1) * 4 + kp) * 64 + arow) * 64;
      wr[0] = *(const f32x4*)(wbase + quad * 8);
      wr[1] = *(const f32x4*)(wbase + quad * 8 + 4);
      wr[2] = *(const f32x4*)(wbase + 32 + quad * 8);
      wr[3] = *(const f32x4*)(wbase + 36 + quad * 8);
    }
#pragma unroll
    for (int nt = 0; nt < 4; nt++) {
      const bf16x8 bh0 = *(const bf16x8*)&Tth[k * SLOT + (nt * 16 + col) * 72 + quad * 8];
      const bf16x8 bl0 = *(const bf16x8*)&Ttl[k * SLOT + (nt * 16 + col) * 72 + quad * 8];
      dc[nt] = __builtin_amdgcn_mfma_f32_16x16x32_bf16(awh0, bh0, dc[nt], 0, 0, 0);
      dc[nt] = __builtin_amdgcn_mfma_f32_16x16x32_bf16(awh0, bl0, dc[nt], 0, 0, 0);
      dc[nt] = __builtin_amdgcn_mfma_f32_16x16x32_bf16(awl0, bh0, dc[nt], 0, 0, 0);
      const bf16x8 bh1 = *(const bf16x8*)&Tth[k * SLOT + (nt * 16 + col) * 72 + 32 + quad * 8];
      const bf16x8 bl1 = *(const bf16x8*)&Ttl[k * SLOT + (nt * 16 + col) * 72 + 32 + quad * 8];
      dc[nt] = __builtin_amdgcn_mfma_f32_16x16x32_bf16(awh1, bh1, dc[nt], 0, 0, 0);
      dc[nt] = __builtin_amdgcn_mfma_f32_16x16x32_bf16(awh1, bl1, dc[nt], 0, 0, 0);
      dc[nt] = __builtin_amdgcn_mfma_f32_16x16x32_bf16(awl1, bh1, dc[nt], 0, 0, 0);
    }
    if (tid < 64) {
      const float* wrow = Wm2 + (long)((k * 4 + kp) * 64 + tid) * 64;
      float pc = 0.f;
#pragma unroll
      for (int u4 = 0; u4 < 16; u4++) {
        const f32x4 wv = *(const f32x4*)(wrow + u4 * 4);
        pc += wv[0] * cAv[k * 64 + u4 * 4]     + wv[1] * cAv[k * 64 + u4 * 4 + 1] +
              wv[2] * cAv[k * 64 + u4 * 4 + 2] + wv[3] * cAv[k * 64 + u4 * 4 + 3];
      }
      c4acc += inv * pc + bm2[(k * 4 + kp) * 64 + tid];
    }
  }
  __syncthreads();

  // write T4 into slot 0; publish c4
#pragma unroll
  for (int nt = 0; nt < 4; nt++)
#pragma unroll
    for (int r = 0; r < 4; r++) {
      const float val = dc[nt][r];
      const unsigned short h = f2bf(val);
      const int w_ = nt * 16 + col, v_ = it * 16 + quad * 4 + r;
      Tth[w_ * 72 + v_] = h;
      Ttl[w_ * 72 + v_] = f2bf(val - bf2f(h));
    }
  if (tid < 64) cBv[tid] = c4acc;
  __syncthreads();

  // q4 -> qvv[4]
  {
    float qp = qpart(Tth, Ttl, it, col, quad, Greg);
    if (tid < 64) {
      float sd = 0.f;
      for (int w = 0; w < 64; w++)
        sd += slv[w] * (bf2f(Tth[w * 72 + tid]) + bf2f(Ttl[w * 72 + tid]));
      const float c = cBv[tid];
      qp += c * (2.f * sd + BF * c);
    }
    blkred(qp, red4, qvv, 4, tid, lane, it);
  }
  const float inv4 = qvv[4];

  // output: P4[k'] = inv4 * (Wout_{k'} @ T4)
  {
    f32x4 dcO[4];
#pragma unroll
    for (int nt = 0; nt < 4; nt++) dcO[nt] = (f32x4){0.f, 0.f, 0.f, 0.f};
    const float* wbase = Wout + (long)(kp * 64 + arow) * 64;
    const f32x4 w0 = *(const f32x4*)(wbase + quad * 8);
    const f32x4 w1 = *(const f32x4*)(wbase + quad * 8 + 4);
    const f32x4 w2 = *(const f32x4*)(wbase + 32 + quad * 8);
    const f32x4 w3 = *(const f32x4*)(wbase + 36 + quad * 8);
    bf16x8 awh0, awl0, awh1, awl1;
    split8(w0, w1, inv4, awh0, awl0);
    split8(w2, w3, inv4, awh1, awl1);
#pragma unroll
    for (int nt = 0; nt < 4; nt++) {
      const bf16x8 bh0 = *(const bf16x8*)&Tth[(nt * 16 + col) * 72 + quad * 8];
      const bf16x8 bl0 = *(const bf16x8*)&Ttl[(nt * 16 + col) * 72 + quad * 8];
      dcO[nt] = __builtin_amdgcn_mfma_f32_16x16x32_bf16(awh0, bh0, dcO[nt], 0, 0, 0);
      dcO[nt] = __builtin_amdgcn_mfma_f32_16x16x32_bf16(awh0, bl0, dcO[nt], 0, 0, 0);
      dcO[nt] = __builtin_amdgcn_mfma_f32_16x16x32_bf16(awl0, bh0, dcO[nt], 0, 0, 0);
      const bf16x8 bh1 = *(const bf16x8*)&Tth[(nt * 16 + col) * 72 + 32 + quad * 8];
      const bf16x8 bl1 = *(const bf16x8*)&Ttl[(nt * 16 + col) * 72 + 32 + quad * 8];
      dcO[nt] = __builtin_amdgcn_mfma_f32_16x16x32_bf16(awh1, bh1, dcO[nt], 0, 0, 0);
      dcO[nt] = __builtin_amdgcn_mfma_f32_16x16x32_bf16(awh1, bl1, dcO[nt], 0, 0, 0);
      dcO[nt] = __builtin_amdgcn_mfma_f32_16x16x32_bf16(awl1, bh1, dcO[nt], 0, 0, 0);
    }
    float* po = Pout + (long)kp * 4096;
#pragma unroll
    for (int nt = 0; nt < 4; nt++)
#pragma unroll
      for (int r = 0; r < 4; r++)
        po[(it * 16 + quad * 4 + r) * 64 + nt * 16 + col] = dcO[nt][r];
    if (tid < 64) {
      const float* wrow = Wout + (long)(kp * 64 + tid) * 64;
      float pc = 0.f;
#pragma unroll
      for (int u4 = 0; u4 < 16; u4++) {
        const f32x4 wv = *(const f32x4*)(wrow + u4 * 4);
        pc += wv[0] * cBv[u4 * 4]     + wv[1] * cBv[u4 * 4 + 1] +
              wv[2] * cBv[u4 * 4 + 2] + wv[3] * cBv[u4 * 4 + 3];
      }
      cpout[kp * 64 + tid] = inv4 * pc + bout[kp * 64 + tid];
    }
  }

  // ---- last-block-done tail: final norm (formerly kNorm) -------------------
  __threadfence();
  __syncthreads();
  if (tid == 0) isLast = (atomicAdd(ctr, 1) == 3);
  __syncthreads();
  if (!isLast) return;
  __threadfence();

  float* Tfin = (float*)(Tth + 2 * SLOT);   // 64*68 f32 = 17408 B in slots 2-3
#pragma unroll
  for (int m = 0; m < 16; m++) {
    const int li = m * 256 + tid;
    Tfin[(li >> 6) * 68 + (li & 63)] =
        Pout[li] + Pout[4096 + li] + Pout[8192 + li] + Pout[12288 + li];
  }
  if (tid < 64)
    cBv[tid] = cpout[tid] + cpout[64 + tid] + cpout[128 + tid] + cpout[192 + tid];
  __syncthreads();
  {
    const int tc = tid >> 2, rb = (tid & 3) * 16;
#pragma unroll
    for (int j = 0; j < 16; j++) {
      const float tv = Tfin[(rb + j) * 68 + tc];
      const unsigned short h = f2bf(tv);
      Tth[tc * 72 + rb + j] = h;
      Ttl[tc * 72 + rb + j] = f2bf(tv - bf2f(h));
    }
  }
  __syncthreads();
  {
    float qp = qpart(Tth, Ttl, it, col, quad, Greg);
    if (tid < 64) {
      float sd = 0.f;
      for (int w = 0; w < 64; w++)
        sd += slv[w] * (bf2f(Tth[w * 72 + tid]) + bf2f(Ttl[w * 72 + tid]));
      const float c = cBv[tid];
      qp += c * (2.f * sd + BF * c);
    }
    blkred(qp, red4, qvv, 5, tid, lane, it);
  }
  const float invo = qvv[5];
#pragma unroll
  for (int m = 0; m < 16; m++) {
    const int li = m * 256 + tid;
    MoS[li] = invo * Tfin[(li >> 6) * 68 + (li & 63)];
  }
  if (tid < 64) coS[tid] = invo * cBv[tid];
}

// ---------- kApply: out[b][v] = x[b] @ MoS[:,v] + coS[v] (bf16-x input) -----
__global__ __launch_bounds__(256) void kApply(const unsigned short* __restrict__ x16,
                                              const float* __restrict__ MoS,
                                              const float* __restrict__ coS,
                                              float* __restrict__ out) {
  const int tid = threadIdx.x, lane = tid & 63, vt = tid >> 6;
  const int col = lane & 15, q = lane >> 4;

  bf16x8 bfr[2];
  const float* mr = MoS + (vt * 16 + col) * 64 + q * 8;
  bfr[0] = cvt8(*(const f32x4*)mr, *(const f32x4*)(mr + 4), 1.f);
  bfr[1] = cvt8(*(const f32x4*)(mr + 32), *(const f32x4*)(mr + 36), 1.f);
  const float cf = coS[vt * 16 + col];

  for (int t = 0; t < 16; t++) {
    const int b0 = (blockIdx.x * 16 + t) * 16;
    const unsigned short* xr = x16 + (long)(b0 + col) * 64 + q * 8;
    const bf16x8 a0 = *(const bf16x8*)xr;
    const bf16x8 a1 = *(const bf16x8*)(xr + 32);
    f32x4 acc = (f32x4){0.f, 0.f, 0.f, 0.f};
    acc = __builtin_amdgcn_mfma_f32_16x16x32_bf16(a0, bfr[0], acc, 0, 0, 0);
    acc = __builtin_amdgcn_mfma_f32_16x16x32_bf16(a1, bfr[1], acc, 0, 0, 0);
#pragma unroll
    for (int r = 0; r < 4; r++)
      out[(long)(b0 + q * 4 + r) * 64 + vt * 16 + col] = acc[r] + cf;
  }
}

extern "C" void kernel_launch(void* const* d_in, const int* in_sizes, int n_in,
                              void* d_out, int out_size, void* d_ws, size_t ws_size,
                              hipStream_t stream) {
  const float* x    = (const float*)d_in[0];
  const float* Win  = (const float*)d_in[1];
  const float* bin  = (const float*)d_in[2];
  const float* Wmid = (const float*)d_in[3];
  const float* bmid = (const float*)d_in[4];
  const float* Wout = (const float*)d_in[5];
  const float* bout = (const float*)d_in[6];
  float* out = (float*)d_out;
  float* ws  = (float*)d_ws;
  float* Gpart = out;   // 8.5 MB scratch inside d_out; fully overwritten by kApply
  unsigned short* x16 = (unsigned short*)(ws + OFF_X16);
  int* ctr = (int*)(ws + OFF_CTR);

  const size_t SMEM = (size_t)(8 * SLOT) * 2 + 396 * 4 + 64;   // ~75.4 KB
  hipFuncSetAttribute((const void*)kChainA,
                      hipFuncAttributeMaxDynamicSharedMemorySize, (int)SMEM);
  hipFuncSetAttribute((const void*)kChainB,
                      hipFuncAttributeMaxDynamicSharedMemorySize, (int)SMEM);

  hipMemsetAsync(ctr, 0, sizeof(int), stream);
  kG   <<<512, 256, 0, stream>>>(x, Gpart, x16);
  kGred<<<65, 256, 0, stream>>>(Gpart, ws + OFF_G, ws + OFF_S);
  kChainA<<<16, 256, SMEM, stream>>>(Win, bin, Wmid, bmid, Wmid + 65536, bmid + 1024,
                                     ws + OFF_G, ws + OFF_S, ws + OFF_P2, ws + OFF_C2);
  kChainB<<<4, 256, SMEM, stream>>>(ws + OFF_P2, ws + OFF_C2,
                                    Wmid + 131072, bmid + 2048, Wout, bout,
                                    ws + OFF_G, ws + OFF_S, ws + OFF_P4, ws + OFF_C4,
                                    ws + OFF_MO, ws + OFF_CO, ctr);
  kApply<<<1024, 256, 0, stream>>>(x16, ws + OFF_MO, ws + OFF_CO, out);
}

// Round 10
// 231.422 us; speedup vs baseline: 1.0398x; 1.0398x over previous
//
#include <hip/hip_runtime.h>

// GraphNN collapsed to exact affine form:
//   out = (x @ Mo + co) / n_out; norms from G = x^T x, s = colsum(x):
//   n^2 = sum_{w,w'} G[w][w']*H[w][w'] + c-terms,  H = Tt Tt^T.
// Round 10: R8 structure (best, 230.8) with coalesced T-builds:
// chainA T1 / chainB T3 loaded via coalesced f32x4 -> LDS Tf -> split+transpose
// (was: scalar stride-256B global reads). R9's threadfence tail + x16 relay
// reverted (threadfence caused a ~50us idle L2-writeback stall in chainB).

#define BF 262144.0f
#define SLOT 4608           // 64*72 u16 per matrix slot

// ws float offsets
#define OFF_G   0
#define OFF_S   4096
#define OFF_P2  8192        // 16 slots * 4096
#define OFF_C2  73728       // 1024
#define OFF_P4  74752       // 4 slots * 4096
#define OFF_C4  91136       // 256
#define OFF_MO  91392       // 4096
#define OFF_CO  95488       // 64

typedef __attribute__((ext_vector_type(8))) short bf16x8;   // 8 bf16 = 4 VGPRs
typedef __attribute__((ext_vector_type(4))) float f32x4;

__device__ __forceinline__ unsigned short f2bf(float f) {
  unsigned u = __builtin_bit_cast(unsigned, f);
  u += 0x7FFF + ((u >> 16) & 1);          // round-to-nearest-even
  return (unsigned short)(u >> 16);
}
__device__ __forceinline__ float bf2f(unsigned short h) {
  unsigned u = ((unsigned)h) << 16;
  return __builtin_bit_cast(float, u);
}

__device__ __forceinline__ bf16x8 cvt8(f32x4 a, f32x4 b, float s) {
  bf16x8 t;
#pragma unroll
  for (int j = 0; j < 4; j++) {
    t[j]     = (short)f2bf(a[j] * s);
    t[j + 4] = (short)f2bf(b[j] * s);
  }
  return t;
}

// split 8 floats (scaled) into hi/lo bf16x8
__device__ __forceinline__ void split8(f32x4 a, f32x4 b, float sc,
                                       bf16x8& hi, bf16x8& lo) {
#pragma unroll
  for (int j = 0; j < 4; j++) {
    float v = a[j] * sc;
    unsigned short h = f2bf(v);
    hi[j] = (short)h; lo[j] = (short)f2bf(v - bf2f(h));
    v = b[j] * sc;
    h = f2bf(v);
    hi[j + 4] = (short)h; lo[j + 4] = (short)f2bf(v - bf2f(h));
  }
}

// q MFMA part: sum_{w,w'} G[w][w'] * (Tt Tt^T)[w][w'] for one T-slot
__device__ __forceinline__ float qpart(const unsigned short* th,
                                       const unsigned short* tl,
                                       int it, int col, int quad,
                                       const float Greg[4][4]) {
  f32x4 dq[4];
#pragma unroll
  for (int ut = 0; ut < 4; ut++) dq[ut] = (f32x4){0.f, 0.f, 0.f, 0.f};
#pragma unroll
  for (int ks = 0; ks < 2; ks++) {
    const bf16x8 ah = *(const bf16x8*)&th[(it * 16 + col) * 72 + ks * 32 + quad * 8];
    const bf16x8 al = *(const bf16x8*)&tl[(it * 16 + col) * 72 + ks * 32 + quad * 8];
#pragma unroll
    for (int ut = 0; ut < 4; ut++) {
      const bf16x8 bh = *(const bf16x8*)&th[(ut * 16 + col) * 72 + ks * 32 + quad * 8];
      const bf16x8 bl = *(const bf16x8*)&tl[(ut * 16 + col) * 72 + ks * 32 + quad * 8];
      dq[ut] = __builtin_amdgcn_mfma_f32_16x16x32_bf16(ah, bh, dq[ut], 0, 0, 0);
      dq[ut] = __builtin_amdgcn_mfma_f32_16x16x32_bf16(ah, bl, dq[ut], 0, 0, 0);
      dq[ut] = __builtin_amdgcn_mfma_f32_16x16x32_bf16(al, bh, dq[ut], 0, 0, 0);
    }
  }
  float qp = 0.f;
#pragma unroll
  for (int ut = 0; ut < 4; ut++)
#pragma unroll
    for (int r = 0; r < 4; r++) qp += dq[ut][r] * Greg[ut][r];
  return qp;
}

// block reduction of qp -> qvv[idx] = 1/sqrt(sum); uniform control flow
__device__ __forceinline__ void blkred(float qp, float* red4, float* qvv,
                                       int idx, int tid, int lane, int it) {
#pragma unroll
  for (int off = 32; off; off >>= 1) qp += __shfl_down(qp, off, 64);
  if (lane == 0) red4[it] = qp;
  __syncthreads();
  if (tid == 0) qvv[idx] = 1.0f / sqrtf(red4[0] + red4[1] + red4[2] + red4[3]);
  __syncthreads();
}

// ---------- kG: per-block partial G = x^T x (bf16 MFMA) + partial colsum ----
__global__ __launch_bounds__(256) void kG(const float* __restrict__ x,
                                          float* __restrict__ Gpart) {
  __shared__ __align__(16) unsigned short xts[4][4][16][8];
  __shared__ float sred[256][4];
  const int tid = threadIdx.x;
  const int lane = tid & 63, mt = tid >> 6;
  const int col = lane & 15, q = lane >> 4;
  const int row0 = tid >> 4;
  const int cf0  = (tid & 15) * 4;

  f32x4 acc[4];
#pragma unroll
  for (int nt = 0; nt < 4; nt++) acc[nt] = (f32x4){0.f, 0.f, 0.f, 0.f};
  float s0 = 0.f, s1 = 0.f, s2 = 0.f, s3 = 0.f;

  const float* bx = x + (long)blockIdx.x * 32768;   // 512 rows
  f32x4 r0 = *(const f32x4*)(bx + tid * 4);
  f32x4 r1 = *(const f32x4*)(bx + 1024 + tid * 4);

  for (int c = 0; c < 16; c++) {
    __syncthreads();
    s0 += r0[0] + r1[0]; s1 += r0[1] + r1[1];
    s2 += r0[2] + r1[2]; s3 += r0[3] + r1[3];
#pragma unroll
    for (int j = 0; j < 4; j++) {
      const int cf = cf0 + j;
      xts[cf >> 4][row0 >> 3][cf & 15][row0 & 7]        = f2bf(r0[j]);
      xts[cf >> 4][2 + (row0 >> 3)][cf & 15][row0 & 7]  = f2bf(r1[j]);
    }
    f32x4 r0n = r0, r1n = r1;
    if (c < 15) {
      r0n = *(const f32x4*)(bx + (c + 1) * 2048 + tid * 4);
      r1n = *(const f32x4*)(bx + (c + 1) * 2048 + 1024 + tid * 4);
    }
    __syncthreads();
    const bf16x8 af = *(const bf16x8*)xts[mt][q][col];
#pragma unroll
    for (int nt = 0; nt < 4; nt++) {
      const bf16x8 bfr = *(const bf16x8*)xts[nt][q][col];
      acc[nt] = __builtin_amdgcn_mfma_f32_16x16x32_bf16(af, bfr, acc[nt], 0, 0, 0);
    }
    r0 = r0n; r1 = r1n;
  }

  float* myp = Gpart + (long)blockIdx.x * 4160;
#pragma unroll
  for (int nt = 0; nt < 4; nt++)
#pragma unroll
    for (int r = 0; r < 4; r++)
      myp[(mt * 16 + q * 4 + r) * 64 + nt * 16 + col] = acc[nt][r];

  sred[tid][0] = s0; sred[tid][1] = s1; sred[tid][2] = s2; sred[tid][3] = s3;
  __syncthreads();
  if (tid < 64) {
    float t = 0.f;
#pragma unroll
    for (int k2 = 0; k2 < 16; k2++) t += sred[(tid >> 2) + 16 * k2][tid & 3];
    myp[4096 + tid] = t;
  }
}

// ---------- kGred: reduce 512 partials -> G, s (coalesced) ------------------
__global__ __launch_bounds__(256) void kGred(const float* __restrict__ Gpart,
                                             float* __restrict__ G,
                                             float* __restrict__ s) {
  __shared__ float red[4][64];
  const int tid = threadIdx.x;
  const int e = blockIdx.x * 64 + (tid & 63);
  const int quarter = tid >> 6;
  float acc = 0.f;
#pragma unroll 4
  for (int j = 0; j < 128; j++)
    acc += Gpart[(long)(quarter * 128 + j) * 4160 + e];
  red[quarter][tid & 63] = acc;
  __syncthreads();
  if (tid < 64) {
    const float t = red[0][tid] + red[1][tid] + red[2][tid] + red[3][tid];
    const int ee = blockIdx.x * 64 + tid;
    if (ee < 4096) G[ee] = t;
    else           s[ee - 4096] = t;
  }
}

// ---------- kChainA: levels 1+2. Block (p2,k2). ----------------------------
__global__ __launch_bounds__(256) void kChainA(
    const float* __restrict__ Win, const float* __restrict__ bin,
    const float* __restrict__ Wm0, const float* __restrict__ bm0,
    const float* __restrict__ Wm1, const float* __restrict__ bm1,
    const float* __restrict__ G, const float* __restrict__ s,
    float* __restrict__ Pout, float* __restrict__ cpout) {
  extern __shared__ __align__(16) char smem[];
  unsigned short* Tth = (unsigned short*)smem;
  unsigned short* Ttl = Tth + 4 * SLOT;
  float* cAv  = (float*)(Ttl + 4 * SLOT);   // 256
  float* cBv  = cAv + 256;                  // 64
  float* slv  = cBv + 64;                   // 64
  float* red4 = slv + 64;                   // 4
  float* qvv  = red4 + 4;                   // 8
  float* Tf   = qvv + 8;                    // 64*68

  const int tid = threadIdx.x;
  const int p2 = blockIdx.x >> 2, k2 = blockIdx.x & 3;
  const int lane = tid & 63, it = tid >> 6;
  const int col = lane & 15, quad = lane >> 4;

  float Greg[4][4];
#pragma unroll
  for (int ut = 0; ut < 4; ut++)
#pragma unroll
    for (int r = 0; r < 4; r++)
      Greg[ut][r] = G[(it * 16 + quad * 4 + r) * 64 + ut * 16 + col];
  if (tid < 64) slv[tid] = s[tid];
  if (tid < 256) cAv[tid] = bin[tid];      // c1[p][v], contiguous

  // build T1 slots: coalesced f32x4 -> Tf, then split+transpose (R6 pattern)
  for (int p = 0; p < 4; p++) {
#pragma unroll
    for (int m = 0; m < 4; m++) {
      const int li = m * 1024 + tid * 4;
      *(f32x4*)&Tf[(li >> 6) * 68 + (li & 63)] = *(const f32x4*)(Win + p * 4096 + li);
    }
    __syncthreads();
    const int tc = tid >> 2, rb = (tid & 3) * 16;
#pragma unroll
    for (int j = 0; j < 16; j++) {
      const float tv = Tf[(rb + j) * 68 + tc];
      const unsigned short h = f2bf(tv);
      Tth[p * SLOT + tc * 72 + rb + j] = h;
      Ttl[p * SLOT + tc * 72 + rb + j] = f2bf(tv - bf2f(h));
    }
    __syncthreads();
  }

  // q1_p -> qvv[0..3]
#pragma unroll
  for (int p = 0; p < 4; p++) {
    float qp = qpart(Tth + p * SLOT, Ttl + p * SLOT, it, col, quad, Greg);
    if (tid < 64) {
      float sd = 0.f;
      for (int w = 0; w < 64; w++)
        sd += slv[w] * (bf2f(Tth[p * SLOT + w * 72 + tid]) +
                        bf2f(Ttl[p * SLOT + w * 72 + tid]));
      const float c = cAv[p * 64 + tid];
      qp += c * (2.f * sd + BF * c);
    }
    blkred(qp, red4, qvv, p, tid, lane, it);
  }

  // compose T2_p2 = sum_p inv1_p * (Wm0_{p,p2} @ T1_p); c2 in parallel
  f32x4 dc[4];
#pragma unroll
  for (int nt = 0; nt < 4; nt++) dc[nt] = (f32x4){0.f, 0.f, 0.f, 0.f};
  float c2acc = 0.f;

  const int arow = it * 16 + col;
  f32x4 wr[4];
  {
    const float* wbase = Wm0 + (long)((0 * 4 + p2) * 64 + arow) * 64;
    wr[0] = *(const f32x4*)(wbase + quad * 8);
    wr[1] = *(const f32x4*)(wbase + quad * 8 + 4);
    wr[2] = *(const f32x4*)(wbase + 32 + quad * 8);
    wr[3] = *(const f32x4*)(wbase + 36 + quad * 8);
  }
#pragma unroll
  for (int p = 0; p < 4; p++) {
    const float inv = qvv[p];
    bf16x8 awh0, awl0, awh1, awl1;
    split8(wr[0], wr[1], inv, awh0, awl0);
    split8(wr[2], wr[3], inv, awh1, awl1);
    if (p < 3) {
      const float* wbase = Wm0 + (long)(((p + 1) * 4 + p2) * 64 + arow) * 64;
      wr[0] = *(const f32x4*)(wbase + quad * 8);
      wr[1] = *(const f32x4*)(wbase + quad * 8 + 4);
      wr[2] = *(const f32x4*)(wbase + 32 + quad * 8);
      wr[3] = *(const f32x4*)(wbase + 36 + quad * 8);
    }
#pragma unroll
    for (int nt = 0; nt < 4; nt++) {
      const bf16x8 bh0 = *(const bf16x8*)&Tth[p * SLOT + (nt * 16 + col) * 72 + quad * 8];
      const bf16x8 bl0 = *(const bf16x8*)&Ttl[p * SLOT + (nt * 16 + col) * 72 + quad * 8];
      dc[nt] = __builtin_amdgcn_mfma_f32_16x16x32_bf16(awh0, bh0, dc[nt], 0, 0, 0);
      dc[nt] = __builtin_amdgcn_mfma_f32_16x16x32_bf16(awh0, bl0, dc[nt], 0, 0, 0);
      dc[nt] = __builtin_amdgcn_mfma_f32_16x16x32_bf16(awl0, bh0, dc[nt], 0, 0, 0);
      const bf16x8 bh1 = *(const bf16x8*)&Tth[p * SLOT + (nt * 16 + col) * 72 + 32 + quad * 8];
      const bf16x8 bl1 = *(const bf16x8*)&Ttl[p * SLOT + (nt * 16 + col) * 72 + 32 + quad * 8];
      dc[nt] = __builtin_amdgcn_mfma_f32_16x16x32_bf16(awh1, bh1, dc[nt], 0, 0, 0);
      dc[nt] = __builtin_amdgcn_mfma_f32_16x16x32_bf16(awh1, bl1, dc[nt], 0, 0, 0);
      dc[nt] = __builtin_amdgcn_mfma_f32_16x16x32_bf16(awl1, bh1, dc[nt], 0, 0, 0);
    }
    if (tid < 64) {
      const float* wrow = Wm0 + (long)((p * 4 + p2) * 64 + tid) * 64;
      float pc = 0.f;
#pragma unroll
      for (int u4 = 0; u4 < 16; u4++) {
        const f32x4 wv = *(const f32x4*)(wrow + u4 * 4);
        pc += wv[0] * cAv[p * 64 + u4 * 4]     + wv[1] * cAv[p * 64 + u4 * 4 + 1] +
              wv[2] * cAv[p * 64 + u4 * 4 + 2] + wv[3] * cAv[p * 64 + u4 * 4 + 3];
      }
      c2acc += inv * pc + bm0[(p * 4 + p2) * 64 + tid];
    }
  }
  __syncthreads();    // all slot reads done before overwriting slot 0

  // write T2 (split+transposed) into slot 0; publish c2
#pragma unroll
  for (int nt = 0; nt < 4; nt++)
#pragma unroll
    for (int r = 0; r < 4; r++) {
      const float val = dc[nt][r];
      const unsigned short h = f2bf(val);
      const int w_ = nt * 16 + col, v_ = it * 16 + quad * 4 + r;
      Tth[w_ * 72 + v_] = h;
      Ttl[w_ * 72 + v_] = f2bf(val - bf2f(h));
    }
  if (tid < 64) cBv[tid] = c2acc;
  __syncthreads();

  // q2 -> qvv[4]
  {
    float qp = qpart(Tth, Ttl, it, col, quad, Greg);
    if (tid < 64) {
      float sd = 0.f;
      for (int w = 0; w < 64; w++)
        sd += slv[w] * (bf2f(Tth[w * 72 + tid]) + bf2f(Ttl[w * 72 + tid]));
      const float c = cBv[tid];
      qp += c * (2.f * sd + BF * c);
    }
    blkred(qp, red4, qvv, 4, tid, lane, it);
  }
  const float inv2 = qvv[4];

  // output: P2[p2][k2] = inv2 * (Wm1_{p2,k2} @ T2)
  {
    f32x4 dcO[4];
#pragma unroll
    for (int nt = 0; nt < 4; nt++) dcO[nt] = (f32x4){0.f, 0.f, 0.f, 0.f};
    const float* wbase = Wm1 + (long)((p2 * 4 + k2) * 64 + arow) * 64;
    const f32x4 w0 = *(const f32x4*)(wbase + quad * 8);
    const f32x4 w1 = *(const f32x4*)(wbase + quad * 8 + 4);
    const f32x4 w2 = *(const f32x4*)(wbase + 32 + quad * 8);
    const f32x4 w3 = *(const f32x4*)(wbase + 36 + quad * 8);
    bf16x8 awh0, awl0, awh1, awl1;
    split8(w0, w1, inv2, awh0, awl0);
    split8(w2, w3, inv2, awh1, awl1);
#pragma unroll
    for (int nt = 0; nt < 4; nt++) {
      const bf16x8 bh0 = *(const bf16x8*)&Tth[(nt * 16 + col) * 72 + quad * 8];
      const bf16x8 bl0 = *(const bf16x8*)&Ttl[(nt * 16 + col) * 72 + quad * 8];
      dcO[nt] = __builtin_amdgcn_mfma_f32_16x16x32_bf16(awh0, bh0, dcO[nt], 0, 0, 0);
      dcO[nt] = __builtin_amdgcn_mfma_f32_16x16x32_bf16(awh0, bl0, dcO[nt], 0, 0, 0);
      dcO[nt] = __builtin_amdgcn_mfma_f32_16x16x32_bf16(awl0, bh0, dcO[nt], 0, 0, 0);
      const bf16x8 bh1 = *(const bf16x8*)&Tth[(nt * 16 + col) * 72 + 32 + quad * 8];
      const bf16x8 bl1 = *(const bf16x8*)&Ttl[(nt * 16 + col) * 72 + 32 + quad * 8];
      dcO[nt] = __builtin_amdgcn_mfma_f32_16x16x32_bf16(awh1, bh1, dcO[nt], 0, 0, 0);
      dcO[nt] = __builtin_amdgcn_mfma_f32_16x16x32_bf16(awh1, bl1, dcO[nt], 0, 0, 0);
      dcO[nt] = __builtin_amdgcn_mfma_f32_16x16x32_bf16(awl1, bh1, dcO[nt], 0, 0, 0);
    }
    float* po = Pout + (long)(p2 * 4 + k2) * 4096;
#pragma unroll
    for (int nt = 0; nt < 4; nt++)
#pragma unroll
      for (int r = 0; r < 4; r++)
        po[(it * 16 + quad * 4 + r) * 64 + nt * 16 + col] = dcO[nt][r];
    if (tid < 64) {
      const float* wrow = Wm1 + (long)((p2 * 4 + k2) * 64 + tid) * 64;
      float pc = 0.f;
#pragma unroll
      for (int u4 = 0; u4 < 16; u4++) {
        const f32x4 wv = *(const f32x4*)(wrow + u4 * 4);
        pc += wv[0] * cBv[u4 * 4]     + wv[1] * cBv[u4 * 4 + 1] +
              wv[2] * cBv[u4 * 4 + 2] + wv[3] * cBv[u4 * 4 + 3];
      }
      cpout[(p2 * 4 + k2) * 64 + tid] = inv2 * pc + bm1[(p2 * 4 + k2) * 64 + tid];
    }
  }
}

// ---------- kChainB: levels 3+4. Block k' = blockIdx.x ----------------------
__global__ __launch_bounds__(256) void kChainB(
    const float* __restrict__ Pin, const float* __restrict__ cpin,
    const float* __restrict__ Wm2, const float* __restrict__ bm2,
    const float* __restrict__ Wout, const float* __restrict__ bout,
    const float* __restrict__ G, const float* __restrict__ s,
    float* __restrict__ Pout, float* __restrict__ cpout) {
  extern __shared__ __align__(16) char smem[];
  unsigned short* Tth = (unsigned short*)smem;
  unsigned short* Ttl = Tth + 4 * SLOT;
  float* cAv  = (float*)(Ttl + 4 * SLOT);   // 256  (c3[k][v])
  float* cBv  = cAv + 256;                  // 64   (c4)
  float* slv  = cBv + 64;                   // 64
  float* red4 = slv + 64;                   // 4
  float* qvv  = red4 + 4;                   // 8
  float* Tf   = qvv + 8;                    // 64*68

  const int tid = threadIdx.x;
  const int kp = blockIdx.x;                // k' (output node of level 4)
  const int lane = tid & 63, it = tid >> 6;
  const int col = lane & 15, quad = lane >> 4;

  float Greg[4][4];
#pragma unroll
  for (int ut = 0; ut < 4; ut++)
#pragma unroll
    for (int r = 0; r < 4; r++)
      Greg[ut][r] = G[(it * 16 + quad * 4 + r) * 64 + ut * 16 + col];
  if (tid < 64) slv[tid] = s[tid];
  if (tid < 256) {
    const int k = tid >> 6, v = tid & 63;
    cAv[tid] = cpin[(0 * 4 + k) * 64 + v] + cpin[(1 * 4 + k) * 64 + v] +
               cpin[(2 * 4 + k) * 64 + v] + cpin[(3 * 4 + k) * 64 + v];
  }

  // build T3 slots: T3_k = sum_p P2[p][k]; coalesced -> Tf -> split+transpose
  for (int k = 0; k < 4; k++) {
#pragma unroll
    for (int m = 0; m < 4; m++) {
      const int li = m * 1024 + tid * 4;
      const f32x4 a = *(const f32x4*)(Pin + (0 * 4 + k) * 4096 + li);
      const f32x4 b = *(const f32x4*)(Pin + (1 * 4 + k) * 4096 + li);
      const f32x4 c = *(const f32x4*)(Pin + (2 * 4 + k) * 4096 + li);
      const f32x4 d = *(const f32x4*)(Pin + (3 * 4 + k) * 4096 + li);
      *(f32x4*)&Tf[(li >> 6) * 68 + (li & 63)] = a + b + c + d;
    }
    __syncthreads();
    const int tc = tid >> 2, rb = (tid & 3) * 16;
#pragma unroll
    for (int j = 0; j < 16; j++) {
      const float tv = Tf[(rb + j) * 68 + tc];
      const unsigned short h = f2bf(tv);
      Tth[k * SLOT + tc * 72 + rb + j] = h;
      Ttl[k * SLOT + tc * 72 + rb + j] = f2bf(tv - bf2f(h));
    }
    __syncthreads();
  }

  // q3_k -> qvv[0..3]
#pragma unroll
  for (int k = 0; k < 4; k++) {
    float qp = qpart(Tth + k * SLOT, Ttl + k * SLOT, it, col, quad, Greg);
    if (tid < 64) {
      float sd = 0.f;
      for (int w = 0; w < 64; w++)
        sd += slv[w] * (bf2f(Tth[k * SLOT + w * 72 + tid]) +
                        bf2f(Ttl[k * SLOT + w * 72 + tid]));
      const float c = cAv[k * 64 + tid];
      qp += c * (2.f * sd + BF * c);
    }
    blkred(qp, red4, qvv, k, tid, lane, it);
  }

  // compose T4_{k'} = sum_k inv3_k * (Wm2_{k,k'} @ T3_k); c4 in parallel
  f32x4 dc[4];
#pragma unroll
  for (int nt = 0; nt < 4; nt++) dc[nt] = (f32x4){0.f, 0.f, 0.f, 0.f};
  float c4acc = 0.f;

  const int arow = it * 16 + col;
  f32x4 wr[4];
  {
    const float* wbase = Wm2 + (long)((0 * 4 + kp) * 64 + arow) * 64;
    wr[0] = *(const f32x4*)(wbase + quad * 8);
    wr[1] = *(const f32x4*)(wbase + quad * 8 + 4);
    wr[2] = *(const f32x4*)(wbase + 32 + quad * 8);
    wr[3] = *(const f32x4*)(wbase + 36 + quad * 8);
  }
#pragma unroll
  for (int k = 0; k < 4; k++) {
    const float inv = qvv[k];
    bf16x8 awh0, awl0, awh1, awl1;
    split8(wr[0], wr[1], inv, awh0, awl0);
    split8(wr[2], wr[3], inv, awh1, awl1);
    if (k < 3) {
      const float* wbase = Wm2 + (long)(((k + 1) * 4 + kp) * 64 + arow) * 64;
      wr[0] = *(const f32x4*)(wbase + quad * 8);
      wr[1] = *(const f32x4*)(wbase + quad * 8 + 4);
      wr[2] = *(const f32x4*)(wbase + 32 + quad * 8);
      wr[3] = *(const f32x4*)(wbase + 36 + quad * 8);
    }
#pragma unroll
    for (int nt = 0; nt < 4; nt++) {
      const bf16x8 bh0 = *(const bf16x8*)&Tth[k * SLOT + (nt * 16 + col) * 72 + quad * 8];
      const bf16x8 bl0 = *(const bf16x8*)&Ttl[k * SLOT + (nt * 16 + col) * 72 + quad * 8];
      dc[nt] = __builtin_amdgcn_mfma_f32_16x16x32_bf16(awh0, bh0, dc[nt], 0, 0, 0);
      dc[nt] = __builtin_amdgcn_mfma_f32_16x16x32_bf16(awh0, bl0, dc[nt], 0, 0, 0);
      dc[nt] = __builtin_amdgcn_mfma_f32_16x16x32_bf16(awl0, bh0, dc[nt], 0, 0, 0);
      const bf16x8 bh1 = *(const bf16x8*)&Tth[k * SLOT + (nt * 16 + col) * 72 + 32 + quad * 8];
      const bf16x8 bl1 = *(const bf16x8*)&Ttl[k * SLOT + (nt * 16 + col) * 72 + 32 + quad * 8];
      dc[nt] = __builtin_amdgcn_mfma_f32_16x16x32_bf16(awh1, bh1, dc[nt], 0, 0, 0);
      dc[nt] = __builtin_amdgcn_mfma_f32_16x16x32_bf16(awh1, bl1, dc[nt], 0, 0, 0);
      dc[nt] = __builtin_amdgcn_mfma_f32_16x16x32_bf16(awl1, bh1, dc[nt], 0, 0, 0);
    }
    if (tid < 64) {
      const float* wrow = Wm2 + (long)((k * 4 + kp) * 64 + tid) * 64;
      float pc = 0.f;
#pragma unroll
      for (int u4 = 0; u4 < 16; u4++) {
        const f32x4 wv = *(const f32x4*)(wrow + u4 * 4);
        pc += wv[0] * cAv[k * 64 + u4 * 4]     + wv[1] * cAv[k * 64 + u4 * 4 + 1] +
              wv[2] * cAv[k * 64 + u4 * 4 + 2] + wv[3] * cAv[k * 64 + u4 * 4 + 3];
      }
      c4acc += inv * pc + bm2[(k * 4 + kp) * 64 + tid];
    }
  }
  __syncthreads();

  // write T4 into slot 0; publish c4
#pragma unroll
  for (int nt = 0; nt < 4; nt++)
#pragma unroll
    for (int r = 0; r < 4; r++) {
      const float val = dc[nt][r];
      const unsigned short h = f2bf(val);
      const int w_ = nt * 16 + col, v_ = it * 16 + quad * 4 + r;
      Tth[w_ * 72 + v_] = h;
      Ttl[w_ * 72 + v_] = f2bf(val - bf2f(h));
    }
  if (tid < 64) cBv[tid] = c4acc;
  __syncthreads();

  // q4 -> qvv[4]
  {
    float qp = qpart(Tth, Ttl, it, col, quad, Greg);
    if (tid < 64) {
      float sd = 0.f;
      for (int w = 0; w < 64; w++)
        sd += slv[w] * (bf2f(Tth[w * 72 + tid]) + bf2f(Ttl[w * 72 + tid]));
      const float c = cBv[tid];
      qp += c * (2.f * sd + BF * c);
    }
    blkred(qp, red4, qvv, 4, tid, lane, it);
  }
  const float inv4 = qvv[4];

  // output: P4[k'] = inv4 * (Wout_{k'} @ T4)
  {
    f32x4 dcO[4];
#pragma unroll
    for (int nt = 0; nt < 4; nt++) dcO[nt] = (f32x4){0.f, 0.f, 0.f, 0.f};
    const float* wbase = Wout + (long)(kp * 64 + arow) * 64;
    const f32x4 w0 = *(const f32x4*)(wbase + quad * 8);
    const f32x4 w1 = *(const f32x4*)(wbase + quad * 8 + 4);
    const f32x4 w2 = *(const f32x4*)(wbase + 32 + quad * 8);
    const f32x4 w3 = *(const f32x4*)(wbase + 36 + quad * 8);
    bf16x8 awh0, awl0, awh1, awl1;
    split8(w0, w1, inv4, awh0, awl0);
    split8(w2, w3, inv4, awh1, awl1);
#pragma unroll
    for (int nt = 0; nt < 4; nt++) {
      const bf16x8 bh0 = *(const bf16x8*)&Tth[(nt * 16 + col) * 72 + quad * 8];
      const bf16x8 bl0 = *(const bf16x8*)&Ttl[(nt * 16 + col) * 72 + quad * 8];
      dcO[nt] = __builtin_amdgcn_mfma_f32_16x16x32_bf16(awh0, bh0, dcO[nt], 0, 0, 0);
      dcO[nt] = __builtin_amdgcn_mfma_f32_16x16x32_bf16(awh0, bl0, dcO[nt], 0, 0, 0);
      dcO[nt] = __builtin_amdgcn_mfma_f32_16x16x32_bf16(awl0, bh0, dcO[nt], 0, 0, 0);
      const bf16x8 bh1 = *(const bf16x8*)&Tth[(nt * 16 + col) * 72 + 32 + quad * 8];
      const bf16x8 bl1 = *(const bf16x8*)&Ttl[(nt * 16 + col) * 72 + 32 + quad * 8];
      dcO[nt] = __builtin_amdgcn_mfma_f32_16x16x32_bf16(awh1, bh1, dcO[nt], 0, 0, 0);
      dcO[nt] = __builtin_amdgcn_mfma_f32_16x16x32_bf16(awh1, bl1, dcO[nt], 0, 0, 0);
      dcO[nt] = __builtin_amdgcn_mfma_f32_16x16x32_bf16(awl1, bh1, dcO[nt], 0, 0, 0);
    }
    float* po = Pout + (long)kp * 4096;
#pragma unroll
    for (int nt = 0; nt < 4; nt++)
#pragma unroll
      for (int r = 0; r < 4; r++)
        po[(it * 16 + quad * 4 + r) * 64 + nt * 16 + col] = dcO[nt][r];
    if (tid < 64) {
      const float* wrow = Wout + (long)(kp * 64 + tid) * 64;
      float pc = 0.f;
#pragma unroll
      for (int u4 = 0; u4 < 16; u4++) {
        const f32x4 wv = *(const f32x4*)(wrow + u4 * 4);
        pc += wv[0] * cBv[u4 * 4]     + wv[1] * cBv[u4 * 4 + 1] +
              wv[2] * cBv[u4 * 4 + 2] + wv[3] * cBv[u4 * 4 + 3];
      }
      cpout[kp * 64 + tid] = inv4 * pc + bout[kp * 64 + tid];
    }
  }
}

// ---------- kNorm: final norm via split MFMA; write scaled Mo/co ------------
__global__ __launch_bounds__(256) void kNorm(const float* __restrict__ Psrc,
                                             const float* __restrict__ csrc,
                                             const float* __restrict__ G,
                                             const float* __restrict__ s,
                                             float* __restrict__ MoS,
                                             float* __restrict__ coS) {
  __shared__ float Tf[64][68];
  __shared__ __align__(16) unsigned short Tth[64][68], Ttl[64][68];
  __shared__ float red[256];
  __shared__ __align__(16) float cl[64], sl[64];
  const int tid = threadIdx.x;
  const int lane = tid & 63, it = tid >> 6;
  const int col = lane & 15, quad = lane >> 4;

  float Greg[4][4];
#pragma unroll
  for (int ut = 0; ut < 4; ut++)
#pragma unroll
    for (int r = 0; r < 4; r++)
      Greg[ut][r] = G[(it * 16 + quad * 4 + r) * 64 + ut * 16 + col];

#pragma unroll
  for (int m = 0; m < 16; m++) {
    const int li = m * 256 + tid;
    Tf[li >> 6][li & 63] = Psrc[li] + Psrc[4096 + li] + Psrc[8192 + li] + Psrc[12288 + li];
  }
  if (tid < 64) {
    cl[tid] = csrc[tid] + csrc[64 + tid] + csrc[128 + tid] + csrc[192 + tid];
    sl[tid] = s[tid];
  }
  __syncthreads();

  {
    const int tc = tid >> 2;
    const int rb = (tid & 3) * 16;
#pragma unroll
    for (int j = 0; j < 16; j++) {
      const float tv = Tf[rb + j][tc];
      const unsigned short h = f2bf(tv);
      Tth[tc][rb + j] = h;
      Ttl[tc][rb + j] = f2bf(tv - bf2f(h));
    }
  }
  __syncthreads();

  float qp = 0.f;
  {
    f32x4 dq[4];
#pragma unroll
    for (int ut = 0; ut < 4; ut++) dq[ut] = (f32x4){0.f, 0.f, 0.f, 0.f};
#pragma unroll
    for (int ks = 0; ks < 2; ks++) {
      const bf16x8 ah = *(const bf16x8*)&Tth[it * 16 + col][ks * 32 + quad * 8];
      const bf16x8 al = *(const bf16x8*)&Ttl[it * 16 + col][ks * 32 + quad * 8];
#pragma unroll
      for (int ut = 0; ut < 4; ut++) {
        const bf16x8 bh = *(const bf16x8*)&Tth[ut * 16 + col][ks * 32 + quad * 8];
        const bf16x8 bl = *(const bf16x8*)&Ttl[ut * 16 + col][ks * 32 + quad * 8];
        dq[ut] = __builtin_amdgcn_mfma_f32_16x16x32_bf16(ah, bh, dq[ut], 0, 0, 0);
        dq[ut] = __builtin_amdgcn_mfma_f32_16x16x32_bf16(ah, bl, dq[ut], 0, 0, 0);
        dq[ut] = __builtin_amdgcn_mfma_f32_16x16x32_bf16(al, bh, dq[ut], 0, 0, 0);
      }
    }
#pragma unroll
    for (int ut = 0; ut < 4; ut++)
#pragma unroll
      for (int r = 0; r < 4; r++)
        qp += dq[ut][r] * Greg[ut][r];
  }
  if (tid < 64) {
    float sd = 0.f;
#pragma unroll
    for (int u4 = 0; u4 < 16; u4++) {
      const f32x4 tv = *(const f32x4*)&Tf[tid][u4 * 4];
      const f32x4 sv = *(const f32x4*)&sl[u4 * 4];
      sd += sv[0] * tv[0] + sv[1] * tv[1] + sv[2] * tv[2] + sv[3] * tv[3];
    }
    qp += cl[tid] * (2.f * sd + BF * cl[tid]);
  }
  red[tid] = qp;
  __syncthreads();
  for (int st = 128; st > 0; st >>= 1) {
    if (tid < st) red[tid] += red[tid + st];
    __syncthreads();
  }
  const float inv = 1.0f / sqrtf(red[0]);

#pragma unroll
  for (int m = 0; m < 16; m++) {
    const int li = m * 256 + tid;
    MoS[li] = inv * Tf[li >> 6][li & 63];
  }
  if (tid < 64) coS[tid] = inv * cl[tid];
}

// ---------- kApply: out[b][v] = x[b] @ MoS[:,v] + coS[v] --------------------
__global__ __launch_bounds__(256) void kApply(const float* __restrict__ x,
                                              const float* __restrict__ MoS,
                                              const float* __restrict__ coS,
                                              float* __restrict__ out) {
  const int tid = threadIdx.x, lane = tid & 63, vt = tid >> 6;
  const int col = lane & 15, q = lane >> 4;

  bf16x8 bfr[2];
  const float* mr = MoS + (vt * 16 + col) * 64 + q * 8;
  bfr[0] = cvt8(*(const f32x4*)mr, *(const f32x4*)(mr + 4), 1.f);
  bfr[1] = cvt8(*(const f32x4*)(mr + 32), *(const f32x4*)(mr + 36), 1.f);
  const float cf = coS[vt * 16 + col];

  for (int t = 0; t < 16; t++) {
    const int b0 = (blockIdx.x * 16 + t) * 16;
    const float* xr = x + (long)(b0 + col) * 64 + q * 8;
    const bf16x8 a0 = cvt8(*(const f32x4*)xr, *(const f32x4*)(xr + 4), 1.f);
    const bf16x8 a1 = cvt8(*(const f32x4*)(xr + 32), *(const f32x4*)(xr + 36), 1.f);
    f32x4 acc = (f32x4){0.f, 0.f, 0.f, 0.f};
    acc = __builtin_amdgcn_mfma_f32_16x16x32_bf16(a0, bfr[0], acc, 0, 0, 0);
    acc = __builtin_amdgcn_mfma_f32_16x16x32_bf16(a1, bfr[1], acc, 0, 0, 0);
#pragma unroll
    for (int r = 0; r < 4; r++)
      out[(long)(b0 + q * 4 + r) * 64 + vt * 16 + col] = acc[r] + cf;
  }
}

extern "C" void kernel_launch(void* const* d_in, const int* in_sizes, int n_in,
                              void* d_out, int out_size, void* d_ws, size_t ws_size,
                              hipStream_t stream) {
  const float* x    = (const float*)d_in[0];
  const float* Win  = (const float*)d_in[1];
  const float* bin  = (const float*)d_in[2];
  const float* Wmid = (const float*)d_in[3];
  const float* bmid = (const float*)d_in[4];
  const float* Wout = (const float*)d_in[5];
  const float* bout = (const float*)d_in[6];
  float* out = (float*)d_out;
  float* ws  = (float*)d_ws;
  float* Gpart = out;   // 8.5 MB scratch inside d_out; fully overwritten by kApply

  const size_t SMEM = (size_t)(8 * SLOT) * 2 + (396 + 8 + 64 * 68) * 4 + 64;  // ~92.8 KB
  hipFuncSetAttribute((const void*)kChainA,
                      hipFuncAttributeMaxDynamicSharedMemorySize, (int)SMEM);
  hipFuncSetAttribute((const void*)kChainB,
                      hipFuncAttributeMaxDynamicSharedMemorySize, (int)SMEM);

  kG   <<<512, 256, 0, stream>>>(x, Gpart);
  kGred<<<65, 256, 0, stream>>>(Gpart, ws + OFF_G, ws + OFF_S);
  kChainA<<<16, 256, SMEM, stream>>>(Win, bin, Wmid, bmid, Wmid + 65536, bmid + 1024,
                                     ws + OFF_G, ws + OFF_S, ws + OFF_P2, ws + OFF_C2);
  kChainB<<<4, 256, SMEM, stream>>>(ws + OFF_P2, ws + OFF_C2,
                                    Wmid + 131072, bmid + 2048, Wout, bout,
                                    ws + OFF_G, ws + OFF_S, ws + OFF_P4, ws + OFF_C4);
  kNorm<<<1, 256, 0, stream>>>(ws + OFF_P4, ws + OFF_C4, ws + OFF_G, ws + OFF_S,
                               ws + OFF_MO, ws + OFF_CO);
  kApply<<<1024, 256, 0, stream>>>(x, ws + OFF_MO, ws + OFF_CO, out);
}

// Round 11
// 227.285 us; speedup vs baseline: 1.0587x; 1.0182x over previous
//
#include <hip/hip_runtime.h>

// GraphNN collapsed to exact affine form:
//   out = (x @ Mo + co) / n_out; norms from G = x^T x, s = colsum(x):
//   n^2 = sum_{w,w'} G[w][w']*H[w][w'] + c-terms,  H = Tt Tt^T.
// Round 11: R10 structure + the R9 x16 relay (kG emits bf16 x copy, kApply
// reads it; L3-resident between the two). R9's threadfence tail stays dropped
// (it caused a 54us L2-writeback stall). 6 dispatches.

#define BF 262144.0f
#define SLOT 4608           // 64*72 u16 per matrix slot

// ws float offsets
#define OFF_G   0
#define OFF_S   4096
#define OFF_P2  8192        // 16 slots * 4096
#define OFF_C2  73728       // 1024
#define OFF_P4  74752       // 4 slots * 4096
#define OFF_C4  91136       // 256
#define OFF_MO  91392       // 4096
#define OFF_CO  95488       // 64
#define OFF_X16 98304       // bf16 x copy: 16.78M u16 = 33.6 MB

typedef __attribute__((ext_vector_type(8))) short bf16x8;   // 8 bf16 = 4 VGPRs
typedef __attribute__((ext_vector_type(4))) float f32x4;
typedef __attribute__((ext_vector_type(4))) unsigned short u16x4;

__device__ __forceinline__ unsigned short f2bf(float f) {
  unsigned u = __builtin_bit_cast(unsigned, f);
  u += 0x7FFF + ((u >> 16) & 1);          // round-to-nearest-even
  return (unsigned short)(u >> 16);
}
__device__ __forceinline__ float bf2f(unsigned short h) {
  unsigned u = ((unsigned)h) << 16;
  return __builtin_bit_cast(float, u);
}

__device__ __forceinline__ bf16x8 cvt8(f32x4 a, f32x4 b, float s) {
  bf16x8 t;
#pragma unroll
  for (int j = 0; j < 4; j++) {
    t[j]     = (short)f2bf(a[j] * s);
    t[j + 4] = (short)f2bf(b[j] * s);
  }
  return t;
}

// split 8 floats (scaled) into hi/lo bf16x8
__device__ __forceinline__ void split8(f32x4 a, f32x4 b, float sc,
                                       bf16x8& hi, bf16x8& lo) {
#pragma unroll
  for (int j = 0; j < 4; j++) {
    float v = a[j] * sc;
    unsigned short h = f2bf(v);
    hi[j] = (short)h; lo[j] = (short)f2bf(v - bf2f(h));
    v = b[j] * sc;
    h = f2bf(v);
    hi[j + 4] = (short)h; lo[j + 4] = (short)f2bf(v - bf2f(h));
  }
}

// q MFMA part: sum_{w,w'} G[w][w'] * (Tt Tt^T)[w][w'] for one T-slot
__device__ __forceinline__ float qpart(const unsigned short* th,
                                       const unsigned short* tl,
                                       int it, int col, int quad,
                                       const float Greg[4][4]) {
  f32x4 dq[4];
#pragma unroll
  for (int ut = 0; ut < 4; ut++) dq[ut] = (f32x4){0.f, 0.f, 0.f, 0.f};
#pragma unroll
  for (int ks = 0; ks < 2; ks++) {
    const bf16x8 ah = *(const bf16x8*)&th[(it * 16 + col) * 72 + ks * 32 + quad * 8];
    const bf16x8 al = *(const bf16x8*)&tl[(it * 16 + col) * 72 + ks * 32 + quad * 8];
#pragma unroll
    for (int ut = 0; ut < 4; ut++) {
      const bf16x8 bh = *(const bf16x8*)&th[(ut * 16 + col) * 72 + ks * 32 + quad * 8];
      const bf16x8 bl = *(const bf16x8*)&tl[(ut * 16 + col) * 72 + ks * 32 + quad * 8];
      dq[ut] = __builtin_amdgcn_mfma_f32_16x16x32_bf16(ah, bh, dq[ut], 0, 0, 0);
      dq[ut] = __builtin_amdgcn_mfma_f32_16x16x32_bf16(ah, bl, dq[ut], 0, 0, 0);
      dq[ut] = __builtin_amdgcn_mfma_f32_16x16x32_bf16(al, bh, dq[ut], 0, 0, 0);
    }
  }
  float qp = 0.f;
#pragma unroll
  for (int ut = 0; ut < 4; ut++)
#pragma unroll
    for (int r = 0; r < 4; r++) qp += dq[ut][r] * Greg[ut][r];
  return qp;
}

// block reduction of qp -> qvv[idx] = 1/sqrt(sum); uniform control flow
__device__ __forceinline__ void blkred(float qp, float* red4, float* qvv,
                                       int idx, int tid, int lane, int it) {
#pragma unroll
  for (int off = 32; off; off >>= 1) qp += __shfl_down(qp, off, 64);
  if (lane == 0) red4[it] = qp;
  __syncthreads();
  if (tid == 0) qvv[idx] = 1.0f / sqrtf(red4[0] + red4[1] + red4[2] + red4[3]);
  __syncthreads();
}

// ---------- kG: partial G = x^T x (bf16 MFMA) + colsum + bf16-x copy --------
__global__ __launch_bounds__(256) void kG(const float* __restrict__ x,
                                          float* __restrict__ Gpart,
                                          unsigned short* __restrict__ x16) {
  __shared__ __align__(16) unsigned short xts[4][4][16][8];
  __shared__ float sred[256][4];
  const int tid = threadIdx.x;
  const int lane = tid & 63, mt = tid >> 6;
  const int col = lane & 15, q = lane >> 4;
  const int row0 = tid >> 4;
  const int cf0  = (tid & 15) * 4;

  f32x4 acc[4];
#pragma unroll
  for (int nt = 0; nt < 4; nt++) acc[nt] = (f32x4){0.f, 0.f, 0.f, 0.f};
  float s0 = 0.f, s1 = 0.f, s2 = 0.f, s3 = 0.f;

  const long brow = (long)blockIdx.x * 512;
  const float* bx = x + brow * 64;
  f32x4 r0 = *(const f32x4*)(bx + tid * 4);
  f32x4 r1 = *(const f32x4*)(bx + 1024 + tid * 4);

  for (int c = 0; c < 16; c++) {
    __syncthreads();
    s0 += r0[0] + r1[0]; s1 += r0[1] + r1[1];
    s2 += r0[2] + r1[2]; s3 += r0[3] + r1[3];
    u16x4 h0, h1;
#pragma unroll
    for (int j = 0; j < 4; j++) {
      const int cf = cf0 + j;
      const unsigned short b0 = f2bf(r0[j]);
      const unsigned short b1 = f2bf(r1[j]);
      h0[j] = b0; h1[j] = b1;
      xts[cf >> 4][row0 >> 3][cf & 15][row0 & 7]        = b0;
      xts[cf >> 4][2 + (row0 >> 3)][cf & 15][row0 & 7]  = b1;
    }
    *(u16x4*)(x16 + (brow + c * 32 + row0) * 64 + cf0)      = h0;
    *(u16x4*)(x16 + (brow + c * 32 + 16 + row0) * 64 + cf0) = h1;
    f32x4 r0n = r0, r1n = r1;
    if (c < 15) {
      r0n = *(const f32x4*)(bx + (c + 1) * 2048 + tid * 4);
      r1n = *(const f32x4*)(bx + (c + 1) * 2048 + 1024 + tid * 4);
    }
    __syncthreads();
    const bf16x8 af = *(const bf16x8*)xts[mt][q][col];
#pragma unroll
    for (int nt = 0; nt < 4; nt++) {
      const bf16x8 bfr = *(const bf16x8*)xts[nt][q][col];
      acc[nt] = __builtin_amdgcn_mfma_f32_16x16x32_bf16(af, bfr, acc[nt], 0, 0, 0);
    }
    r0 = r0n; r1 = r1n;
  }

  float* myp = Gpart + (long)blockIdx.x * 4160;
#pragma unroll
  for (int nt = 0; nt < 4; nt++)
#pragma unroll
    for (int r = 0; r < 4; r++)
      myp[(mt * 16 + q * 4 + r) * 64 + nt * 16 + col] = acc[nt][r];

  sred[tid][0] = s0; sred[tid][1] = s1; sred[tid][2] = s2; sred[tid][3] = s3;
  __syncthreads();
  if (tid < 64) {
    float t = 0.f;
#pragma unroll
    for (int k2 = 0; k2 < 16; k2++) t += sred[(tid >> 2) + 16 * k2][tid & 3];
    myp[4096 + tid] = t;
  }
}

// ---------- kGred: reduce 512 partials -> G, s (coalesced) ------------------
__global__ __launch_bounds__(256) void kGred(const float* __restrict__ Gpart,
                                             float* __restrict__ G,
                                             float* __restrict__ s) {
  __shared__ float red[4][64];
  const int tid = threadIdx.x;
  const int e = blockIdx.x * 64 + (tid & 63);
  const int quarter = tid >> 6;
  float acc = 0.f;
#pragma unroll 4
  for (int j = 0; j < 128; j++)
    acc += Gpart[(long)(quarter * 128 + j) * 4160 + e];
  red[quarter][tid & 63] = acc;
  __syncthreads();
  if (tid < 64) {
    const float t = red[0][tid] + red[1][tid] + red[2][tid] + red[3][tid];
    const int ee = blockIdx.x * 64 + tid;
    if (ee < 4096) G[ee] = t;
    else           s[ee - 4096] = t;
  }
}

// ---------- kChainA: levels 1+2. Block (p2,k2). ----------------------------
__global__ __launch_bounds__(256) void kChainA(
    const float* __restrict__ Win, const float* __restrict__ bin,
    const float* __restrict__ Wm0, const float* __restrict__ bm0,
    const float* __restrict__ Wm1, const float* __restrict__ bm1,
    const float* __restrict__ G, const float* __restrict__ s,
    float* __restrict__ Pout, float* __restrict__ cpout) {
  extern __shared__ __align__(16) char smem[];
  unsigned short* Tth = (unsigned short*)smem;
  unsigned short* Ttl = Tth + 4 * SLOT;
  float* cAv  = (float*)(Ttl + 4 * SLOT);   // 256
  float* cBv  = cAv + 256;                  // 64
  float* slv  = cBv + 64;                   // 64
  float* red4 = slv + 64;                   // 4
  float* qvv  = red4 + 4;                   // 8
  float* Tf   = qvv + 8;                    // 64*68

  const int tid = threadIdx.x;
  const int p2 = blockIdx.x >> 2, k2 = blockIdx.x & 3;
  const int lane = tid & 63, it = tid >> 6;
  const int col = lane & 15, quad = lane >> 4;

  float Greg[4][4];
#pragma unroll
  for (int ut = 0; ut < 4; ut++)
#pragma unroll
    for (int r = 0; r < 4; r++)
      Greg[ut][r] = G[(it * 16 + quad * 4 + r) * 64 + ut * 16 + col];
  if (tid < 64) slv[tid] = s[tid];
  if (tid < 256) cAv[tid] = bin[tid];      // c1[p][v], contiguous

  // build T1 slots: coalesced f32x4 -> Tf, then split+transpose
  for (int p = 0; p < 4; p++) {
#pragma unroll
    for (int m = 0; m < 4; m++) {
      const int li = m * 1024 + tid * 4;
      *(f32x4*)&Tf[(li >> 6) * 68 + (li & 63)] = *(const f32x4*)(Win + p * 4096 + li);
    }
    __syncthreads();
    const int tc = tid >> 2, rb = (tid & 3) * 16;
#pragma unroll
    for (int j = 0; j < 16; j++) {
      const float tv = Tf[(rb + j) * 68 + tc];
      const unsigned short h = f2bf(tv);
      Tth[p * SLOT + tc * 72 + rb + j] = h;
      Ttl[p * SLOT + tc * 72 + rb + j] = f2bf(tv - bf2f(h));
    }
    __syncthreads();
  }

  // q1_p -> qvv[0..3]
#pragma unroll
  for (int p = 0; p < 4; p++) {
    float qp = qpart(Tth + p * SLOT, Ttl + p * SLOT, it, col, quad, Greg);
    if (tid < 64) {
      float sd = 0.f;
      for (int w = 0; w < 64; w++)
        sd += slv[w] * (bf2f(Tth[p * SLOT + w * 72 + tid]) +
                        bf2f(Ttl[p * SLOT + w * 72 + tid]));
      const float c = cAv[p * 64 + tid];
      qp += c * (2.f * sd + BF * c);
    }
    blkred(qp, red4, qvv, p, tid, lane, it);
  }

  // compose T2_p2 = sum_p inv1_p * (Wm0_{p,p2} @ T1_p); c2 in parallel
  f32x4 dc[4];
#pragma unroll
  for (int nt = 0; nt < 4; nt++) dc[nt] = (f32x4){0.f, 0.f, 0.f, 0.f};
  float c2acc = 0.f;

  const int arow = it * 16 + col;
  f32x4 wr[4];
  {
    const float* wbase = Wm0 + (long)((0 * 4 + p2) * 64 + arow) * 64;
    wr[0] = *(const f32x4*)(wbase + quad * 8);
    wr[1] = *(const f32x4*)(wbase + quad * 8 + 4);
    wr[2] = *(const f32x4*)(wbase + 32 + quad * 8);
    wr[3] = *(const f32x4*)(wbase + 36 + quad * 8);
  }
#pragma unroll
  for (int p = 0; p < 4; p++) {
    const float inv = qvv[p];
    bf16x8 awh0, awl0, awh1, awl1;
    split8(wr[0], wr[1], inv, awh0, awl0);
    split8(wr[2], wr[3], inv, awh1, awl1);
    if (p < 3) {
      const float* wbase = Wm0 + (long)(((p + 1) * 4 + p2) * 64 + arow) * 64;
      wr[0] = *(const f32x4*)(wbase + quad * 8);
      wr[1] = *(const f32x4*)(wbase + quad * 8 + 4);
      wr[2] = *(const f32x4*)(wbase + 32 + quad * 8);
      wr[3] = *(const f32x4*)(wbase + 36 + quad * 8);
    }
#pragma unroll
    for (int nt = 0; nt < 4; nt++) {
      const bf16x8 bh0 = *(const bf16x8*)&Tth[p * SLOT + (nt * 16 + col) * 72 + quad * 8];
      const bf16x8 bl0 = *(const bf16x8*)&Ttl[p * SLOT + (nt * 16 + col) * 72 + quad * 8];
      dc[nt] = __builtin_amdgcn_mfma_f32_16x16x32_bf16(awh0, bh0, dc[nt], 0, 0, 0);
      dc[nt] = __builtin_amdgcn_mfma_f32_16x16x32_bf16(awh0, bl0, dc[nt], 0, 0, 0);
      dc[nt] = __builtin_amdgcn_mfma_f32_16x16x32_bf16(awl0, bh0, dc[nt], 0, 0, 0);
      const bf16x8 bh1 = *(const bf16x8*)&Tth[p * SLOT + (nt * 16 + col) * 72 + 32 + quad * 8];
      const bf16x8 bl1 = *(const bf16x8*)&Ttl[p * SLOT + (nt * 16 + col) * 72 + 32 + quad * 8];
      dc[nt] = __builtin_amdgcn_mfma_f32_16x16x32_bf16(awh1, bh1, dc[nt], 0, 0, 0);
      dc[nt] = __builtin_amdgcn_mfma_f32_16x16x32_bf16(awh1, bl1, dc[nt], 0, 0, 0);
      dc[nt] = __builtin_amdgcn_mfma_f32_16x16x32_bf16(awl1, bh1, dc[nt], 0, 0, 0);
    }
    if (tid < 64) {
      const float* wrow = Wm0 + (long)((p * 4 + p2) * 64 + tid) * 64;
      float pc = 0.f;
#pragma unroll
      for (int u4 = 0; u4 < 16; u4++) {
        const f32x4 wv = *(const f32x4*)(wrow + u4 * 4);
        pc += wv[0] * cAv[p * 64 + u4 * 4]     + wv[1] * cAv[p * 64 + u4 * 4 + 1] +
              wv[2] * cAv[p * 64 + u4 * 4 + 2] + wv[3] * cAv[p * 64 + u4 * 4 + 3];
      }
      c2acc += inv * pc + bm0[(p * 4 + p2) * 64 + tid];
    }
  }
  __syncthreads();    // all slot reads done before overwriting slot 0

  // write T2 (split+transposed) into slot 0; publish c2
#pragma unroll
  for (int nt = 0; nt < 4; nt++)
#pragma unroll
    for (int r = 0; r < 4; r++) {
      const float val = dc[nt][r];
      const unsigned short h = f2bf(val);
      const int w_ = nt * 16 + col, v_ = it * 16 + quad * 4 + r;
      Tth[w_ * 72 + v_] = h;
      Ttl[w_ * 72 + v_] = f2bf(val - bf2f(h));
    }
  if (tid < 64) cBv[tid] = c2acc;
  __syncthreads();

  // q2 -> qvv[4]
  {
    float qp = qpart(Tth, Ttl, it, col, quad, Greg);
    if (tid < 64) {
      float sd = 0.f;
      for (int w = 0; w < 64; w++)
        sd += slv[w] * (bf2f(Tth[w * 72 + tid]) + bf2f(Ttl[w * 72 + tid]));
      const float c = cBv[tid];
      qp += c * (2.f * sd + BF * c);
    }
    blkred(qp, red4, qvv, 4, tid, lane, it);
  }
  const float inv2 = qvv[4];

  // output: P2[p2][k2] = inv2 * (Wm1_{p2,k2} @ T2)
  {
    f32x4 dcO[4];
#pragma unroll
    for (int nt = 0; nt < 4; nt++) dcO[nt] = (f32x4){0.f, 0.f, 0.f, 0.f};
    const float* wbase = Wm1 + (long)((p2 * 4 + k2) * 64 + arow) * 64;
    const f32x4 w0 = *(const f32x4*)(wbase + quad * 8);
    const f32x4 w1 = *(const f32x4*)(wbase + quad * 8 + 4);
    const f32x4 w2 = *(const f32x4*)(wbase + 32 + quad * 8);
    const f32x4 w3 = *(const f32x4*)(wbase + 36 + quad * 8);
    bf16x8 awh0, awl0, awh1, awl1;
    split8(w0, w1, inv2, awh0, awl0);
    split8(w2, w3, inv2, awh1, awl1);
#pragma unroll
    for (int nt = 0; nt < 4; nt++) {
      const bf16x8 bh0 = *(const bf16x8*)&Tth[(nt * 16 + col) * 72 + quad * 8];
      const bf16x8 bl0 = *(const bf16x8*)&Ttl[(nt * 16 + col) * 72 + quad * 8];
      dcO[nt] = __builtin_amdgcn_mfma_f32_16x16x32_bf16(awh0, bh0, dcO[nt], 0, 0, 0);
      dcO[nt] = __builtin_amdgcn_mfma_f32_16x16x32_bf16(awh0, bl0, dcO[nt], 0, 0, 0);
      dcO[nt] = __builtin_amdgcn_mfma_f32_16x16x32_bf16(awl0, bh0, dcO[nt], 0, 0, 0);
      const bf16x8 bh1 = *(const bf16x8*)&Tth[(nt * 16 + col) * 72 + 32 + quad * 8];
      const bf16x8 bl1 = *(const bf16x8*)&Ttl[(nt * 16 + col) * 72 + 32 + quad * 8];
      dcO[nt] = __builtin_amdgcn_mfma_f32_16x16x32_bf16(awh1, bh1, dcO[nt], 0, 0, 0);
      dcO[nt] = __builtin_amdgcn_mfma_f32_16x16x32_bf16(awh1, bl1, dcO[nt], 0, 0, 0);
      dcO[nt] = __builtin_amdgcn_mfma_f32_16x16x32_bf16(awl1, bh1, dcO[nt], 0, 0, 0);
    }
    float* po = Pout + (long)(p2 * 4 + k2) * 4096;
#pragma unroll
    for (int nt = 0; nt < 4; nt++)
#pragma unroll
      for (int r = 0; r < 4; r++)
        po[(it * 16 + quad * 4 + r) * 64 + nt * 16 + col] = dcO[nt][r];
    if (tid < 64) {
      const float* wrow = Wm1 + (long)((p2 * 4 + k2) * 64 + tid) * 64;
      float pc = 0.f;
#pragma unroll
      for (int u4 = 0; u4 < 16; u4++) {
        const f32x4 wv = *(const f32x4*)(wrow + u4 * 4);
        pc += wv[0] * cBv[u4 * 4]     + wv[1] * cBv[u4 * 4 + 1] +
              wv[2] * cBv[u4 * 4 + 2] + wv[3] * cBv[u4 * 4 + 3];
      }
      cpout[(p2 * 4 + k2) * 64 + tid] = inv2 * pc + bm1[(p2 * 4 + k2) * 64 + tid];
    }
  }
}

// ---------- kChainB: levels 3+4. Block k' = blockIdx.x ----------------------
__global__ __launch_bounds__(256) void kChainB(
    const float* __restrict__ Pin, const float* __restrict__ cpin,
    const float* __restrict__ Wm2, const float* __restrict__ bm2,
    const float* __restrict__ Wout, const float* __restrict__ bout,
    const float* __restrict__ G, const float* __restrict__ s,
    float* __restrict__ Pout, float* __restrict__ cpout) {
  extern __shared__ __align__(16) char smem[];
  unsigned short* Tth = (unsigned short*)smem;
  unsigned short* Ttl = Tth + 4 * SLOT;
  float* cAv  = (float*)(Ttl + 4 * SLOT);   // 256  (c3[k][v])
  float* cBv  = cAv + 256;                  // 64   (c4)
  float* slv  = cBv + 64;                   // 64
  float* red4 = slv + 64;                   // 4
  float* qvv  = red4 + 4;                   // 8
  float* Tf   = qvv + 8;                    // 64*68

  const int tid = threadIdx.x;
  const int kp = blockIdx.x;                // k' (output node of level 4)
  const int lane = tid & 63, it = tid >> 6;
  const int col = lane & 15, quad = lane >> 4;

  float Greg[4][4];
#pragma unroll
  for (int ut = 0; ut < 4; ut++)
#pragma unroll
    for (int r = 0; r < 4; r++)
      Greg[ut][r] = G[(it * 16 + quad * 4 + r) * 64 + ut * 16 + col];
  if (tid < 64) slv[tid] = s[tid];
  if (tid < 256) {
    const int k = tid >> 6, v = tid & 63;
    cAv[tid] = cpin[(0 * 4 + k) * 64 + v] + cpin[(1 * 4 + k) * 64 + v] +
               cpin[(2 * 4 + k) * 64 + v] + cpin[(3 * 4 + k) * 64 + v];
  }

  // build T3 slots: T3_k = sum_p P2[p][k]; coalesced -> Tf -> split+transpose
  for (int k = 0; k < 4; k++) {
#pragma unroll
    for (int m = 0; m < 4; m++) {
      const int li = m * 1024 + tid * 4;
      const f32x4 a = *(const f32x4*)(Pin + (0 * 4 + k) * 4096 + li);
      const f32x4 b = *(const f32x4*)(Pin + (1 * 4 + k) * 4096 + li);
      const f32x4 c = *(const f32x4*)(Pin + (2 * 4 + k) * 4096 + li);
      const f32x4 d = *(const f32x4*)(Pin + (3 * 4 + k) * 4096 + li);
      *(f32x4*)&Tf[(li >> 6) * 68 + (li & 63)] = a + b + c + d;
    }
    __syncthreads();
    const int tc = tid >> 2, rb = (tid & 3) * 16;
#pragma unroll
    for (int j = 0; j < 16; j++) {
      const float tv = Tf[(rb + j) * 68 + tc];
      const unsigned short h = f2bf(tv);
      Tth[k * SLOT + tc * 72 + rb + j] = h;
      Ttl[k * SLOT + tc * 72 + rb + j] = f2bf(tv - bf2f(h));
    }
    __syncthreads();
  }

  // q3_k -> qvv[0..3]
#pragma unroll
  for (int k = 0; k < 4; k++) {
    float qp = qpart(Tth + k * SLOT, Ttl + k * SLOT, it, col, quad, Greg);
    if (tid < 64) {
      float sd = 0.f;
      for (int w = 0; w < 64; w++)
        sd += slv[w] * (bf2f(Tth[k * SLOT + w * 72 + tid]) +
                        bf2f(Ttl[k * SLOT + w * 72 + tid]));
      const float c = cAv[k * 64 + tid];
      qp += c * (2.f * sd + BF * c);
    }
    blkred(qp, red4, qvv, k, tid, lane, it);
  }

  // compose T4_{k'} = sum_k inv3_k * (Wm2_{k,k'} @ T3_k); c4 in parallel
  f32x4 dc[4];
#pragma unroll
  for (int nt = 0; nt < 4; nt++) dc[nt] = (f32x4){0.f, 0.f, 0.f, 0.f};
  float c4acc = 0.f;

  const int arow = it * 16 + col;
  f32x4 wr[4];
  {
    const float* wbase = Wm2 + (long)((0 * 4 + kp) * 64 + arow) * 64;
    wr[0] = *(const f32x4*)(wbase + quad * 8);
    wr[1] = *(const f32x4*)(wbase + quad * 8 + 4);
    wr[2] = *(const f32x4*)(wbase + 32 + quad * 8);
    wr[3] = *(const f32x4*)(wbase + 36 + quad * 8);
  }
#pragma unroll
  for (int k = 0; k < 4; k++) {
    const float inv = qvv[k];
    bf16x8 awh0, awl0, awh1, awl1;
    split8(wr[0], wr[1], inv, awh0, awl0);
    split8(wr[2], wr[3], inv, awh1, awl1);
    if (k < 3) {
      const float* wbase = Wm2 + (long)(((k + 1) * 4 + kp) * 64 + arow) * 64;
      wr[0] = *(const f32x4*)(wbase + quad * 8);
      wr[1] = *(const f32x4*)(wbase + quad * 8 + 4);
      wr[2] = *(const f32x4*)(wbase + 32 + quad * 8);
      wr[3] = *(const f32x4*)(wbase + 36 + quad * 8);
    }
#pragma unroll
    for (int nt = 0; nt < 4; nt++) {
      const bf16x8 bh0 = *(const bf16x8*)&Tth[k * SLOT + (nt * 16 + col) * 72 + quad * 8];
      const bf16x8 bl0 = *(const bf16x8*)&Ttl[k * SLOT + (nt * 16 + col) * 72 + quad * 8];
      dc[nt] = __builtin_amdgcn_mfma_f32_16x16x32_bf16(awh0, bh0, dc[nt], 0, 0, 0);
      dc[nt] = __builtin_amdgcn_mfma_f32_16x16x32_bf16(awh0, bl0, dc[nt], 0, 0, 0);
      dc[nt] = __builtin_amdgcn_mfma_f32_16x16x32_bf16(awl0, bh0, dc[nt], 0, 0, 0);
      const bf16x8 bh1 = *(const bf16x8*)&Tth[k * SLOT + (nt * 16 + col) * 72 + 32 + quad * 8];
      const bf16x8 bl1 = *(const bf16x8*)&Ttl[k * SLOT + (nt * 16 + col) * 72 + 32 + quad * 8];
      dc[nt] = __builtin_amdgcn_mfma_f32_16x16x32_bf16(awh1, bh1, dc[nt], 0, 0, 0);
      dc[nt] = __builtin_amdgcn_mfma_f32_16x16x32_bf16(awh1, bl1, dc[nt], 0, 0, 0);
      dc[nt] = __builtin_amdgcn_mfma_f32_16x16x32_bf16(awl1, bh1, dc[nt], 0, 0, 0);
    }
    if (tid < 64) {
      const float* wrow = Wm2 + (long)((k * 4 + kp) * 64 + tid) * 64;
      float pc = 0.f;
#pragma unroll
      for (int u4 = 0; u4 < 16; u4++) {
        const f32x4 wv = *(const f32x4*)(wrow + u4 * 4);
        pc += wv[0] * cAv[k * 64 + u4 * 4]     + wv[1] * cAv[k * 64 + u4 * 4 + 1] +
              wv[2] * cAv[k * 64 + u4 * 4 + 2] + wv[3] * cAv[k * 64 + u4 * 4 + 3];
      }
      c4acc += inv * pc + bm2[(k * 4 + kp) * 64 + tid];
    }
  }
  __syncthreads();

  // write T4 into slot 0; publish c4
#pragma unroll
  for (int nt = 0; nt < 4; nt++)
#pragma unroll
    for (int r = 0; r < 4; r++) {
      const float val = dc[nt][r];
      const unsigned short h = f2bf(val);
      const int w_ = nt * 16 + col, v_ = it * 16 + quad * 4 + r;
      Tth[w_ * 72 + v_] = h;
      Ttl[w_ * 72 + v_] = f2bf(val - bf2f(h));
    }
  if (tid < 64) cBv[tid] = c4acc;
  __syncthreads();

  // q4 -> qvv[4]
  {
    float qp = qpart(Tth, Ttl, it, col, quad, Greg);
    if (tid < 64) {
      float sd = 0.f;
      for (int w = 0; w < 64; w++)
        sd += slv[w] * (bf2f(Tth[w * 72 + tid]) + bf2f(Ttl[w * 72 + tid]));
      const float c = cBv[tid];
      qp += c * (2.f * sd + BF * c);
    }
    blkred(qp, red4, qvv, 4, tid, lane, it);
  }
  const float inv4 = qvv[4];

  // output: P4[k'] = inv4 * (Wout_{k'} @ T4)
  {
    f32x4 dcO[4];
#pragma unroll
    for (int nt = 0; nt < 4; nt++) dcO[nt] = (f32x4){0.f, 0.f, 0.f, 0.f};
    const float* wbase = Wout + (long)(kp * 64 + arow) * 64;
    const f32x4 w0 = *(const f32x4*)(wbase + quad * 8);
    const f32x4 w1 = *(const f32x4*)(wbase + quad * 8 + 4);
    const f32x4 w2 = *(const f32x4*)(wbase + 32 + quad * 8);
    const f32x4 w3 = *(const f32x4*)(wbase + 36 + quad * 8);
    bf16x8 awh0, awl0, awh1, awl1;
    split8(w0, w1, inv4, awh0, awl0);
    split8(w2, w3, inv4, awh1, awl1);
#pragma unroll
    for (int nt = 0; nt < 4; nt++) {
      const bf16x8 bh0 = *(const bf16x8*)&Tth[(nt * 16 + col) * 72 + quad * 8];
      const bf16x8 bl0 = *(const bf16x8*)&Ttl[(nt * 16 + col) * 72 + quad * 8];
      dcO[nt] = __builtin_amdgcn_mfma_f32_16x16x32_bf16(awh0, bh0, dcO[nt], 0, 0, 0);
      dcO[nt] = __builtin_amdgcn_mfma_f32_16x16x32_bf16(awh0, bl0, dcO[nt], 0, 0, 0);
      dcO[nt] = __builtin_amdgcn_mfma_f32_16x16x32_bf16(awl0, bh0, dcO[nt], 0, 0, 0);
      const bf16x8 bh1 = *(const bf16x8*)&Tth[(nt * 16 + col) * 72 + 32 + quad * 8];
      const bf16x8 bl1 = *(const bf16x8*)&Ttl[(nt * 16 + col) * 72 + 32 + quad * 8];
      dcO[nt] = __builtin_amdgcn_mfma_f32_16x16x32_bf16(awh1, bh1, dcO[nt], 0, 0, 0);
      dcO[nt] = __builtin_amdgcn_mfma_f32_16x16x32_bf16(awh1, bl1, dcO[nt], 0, 0, 0);
      dcO[nt] = __builtin_amdgcn_mfma_f32_16x16x32_bf16(awl1, bh1, dcO[nt], 0, 0, 0);
    }
    float* po = Pout + (long)kp * 4096;
#pragma unroll
    for (int nt = 0; nt < 4; nt++)
#pragma unroll
      for (int r = 0; r < 4; r++)
        po[(it * 16 + quad * 4 + r) * 64 + nt * 16 + col] = dcO[nt][r];
    if (tid < 64) {
      const float* wrow = Wout + (long)(kp * 64 + tid) * 64;
      float pc = 0.f;
#pragma unroll
      for (int u4 = 0; u4 < 16; u4++) {
        const f32x4 wv = *(const f32x4*)(wrow + u4 * 4);
        pc += wv[0] * cBv[u4 * 4]     + wv[1] * cBv[u4 * 4 + 1] +
              wv[2] * cBv[u4 * 4 + 2] + wv[3] * cBv[u4 * 4 + 3];
      }
      cpout[kp * 64 + tid] = inv4 * pc + bout[kp * 64 + tid];
    }
  }
}

// ---------- kNorm: final norm via split MFMA; write scaled Mo/co ------------
__global__ __launch_bounds__(256) void kNorm(const float* __restrict__ Psrc,
                                             const float* __restrict__ csrc,
                                             const float* __restrict__ G,
                                             const float* __restrict__ s,
                                             float* __restrict__ MoS,
                                             float* __restrict__ coS) {
  __shared__ float Tf[64][68];
  __shared__ __align__(16) unsigned short Tth[64][68], Ttl[64][68];
  __shared__ float red[256];
  __shared__ __align__(16) float cl[64], sl[64];
  const int tid = threadIdx.x;
  const int lane = tid & 63, it = tid >> 6;
  const int col = lane & 15, quad = lane >> 4;

  float Greg[4][4];
#pragma unroll
  for (int ut = 0; ut < 4; ut++)
#pragma unroll
    for (int r = 0; r < 4; r++)
      Greg[ut][r] = G[(it * 16 + quad * 4 + r) * 64 + ut * 16 + col];

#pragma unroll
  for (int m = 0; m < 16; m++) {
    const int li = m * 256 + tid;
    Tf[li >> 6][li & 63] = Psrc[li] + Psrc[4096 + li] + Psrc[8192 + li] + Psrc[12288 + li];
  }
  if (tid < 64) {
    cl[tid] = csrc[tid] + csrc[64 + tid] + csrc[128 + tid] + csrc[192 + tid];
    sl[tid] = s[tid];
  }
  __syncthreads();

  {
    const int tc = tid >> 2;
    const int rb = (tid & 3) * 16;
#pragma unroll
    for (int j = 0; j < 16; j++) {
      const float tv = Tf[rb + j][tc];
      const unsigned short h = f2bf(tv);
      Tth[tc][rb + j] = h;
      Ttl[tc][rb + j] = f2bf(tv - bf2f(h));
    }
  }
  __syncthreads();

  float qp = 0.f;
  {
    f32x4 dq[4];
#pragma unroll
    for (int ut = 0; ut < 4; ut++) dq[ut] = (f32x4){0.f, 0.f, 0.f, 0.f};
#pragma unroll
    for (int ks = 0; ks < 2; ks++) {
      const bf16x8 ah = *(const bf16x8*)&Tth[it * 16 + col][ks * 32 + quad * 8];
      const bf16x8 al = *(const bf16x8*)&Ttl[it * 16 + col][ks * 32 + quad * 8];
#pragma unroll
      for (int ut = 0; ut < 4; ut++) {
        const bf16x8 bh = *(const bf16x8*)&Tth[ut * 16 + col][ks * 32 + quad * 8];
        const bf16x8 bl = *(const bf16x8*)&Ttl[ut * 16 + col][ks * 32 + quad * 8];
        dq[ut] = __builtin_amdgcn_mfma_f32_16x16x32_bf16(ah, bh, dq[ut], 0, 0, 0);
        dq[ut] = __builtin_amdgcn_mfma_f32_16x16x32_bf16(ah, bl, dq[ut], 0, 0, 0);
        dq[ut] = __builtin_amdgcn_mfma_f32_16x16x32_bf16(al, bh, dq[ut], 0, 0, 0);
      }
    }
#pragma unroll
    for (int ut = 0; ut < 4; ut++)
#pragma unroll
      for (int r = 0; r < 4; r++)
        qp += dq[ut][r] * Greg[ut][r];
  }
  if (tid < 64) {
    float sd = 0.f;
#pragma unroll
    for (int u4 = 0; u4 < 16; u4++) {
      const f32x4 tv = *(const f32x4*)&Tf[tid][u4 * 4];
      const f32x4 sv = *(const f32x4*)&sl[u4 * 4];
      sd += sv[0] * tv[0] + sv[1] * tv[1] + sv[2] * tv[2] + sv[3] * tv[3];
    }
    qp += cl[tid] * (2.f * sd + BF * cl[tid]);
  }
  red[tid] = qp;
  __syncthreads();
  for (int st = 128; st > 0; st >>= 1) {
    if (tid < st) red[tid] += red[tid + st];
    __syncthreads();
  }
  const float inv = 1.0f / sqrtf(red[0]);

#pragma unroll
  for (int m = 0; m < 16; m++) {
    const int li = m * 256 + tid;
    MoS[li] = inv * Tf[li >> 6][li & 63];
  }
  if (tid < 64) coS[tid] = inv * cl[tid];
}

// ---------- kApply: out[b][v] = x[b] @ MoS[:,v] + coS[v] (bf16-x input) -----
__global__ __launch_bounds__(256) void kApply(const unsigned short* __restrict__ x16,
                                              const float* __restrict__ MoS,
                                              const float* __restrict__ coS,
                                              float* __restrict__ out) {
  const int tid = threadIdx.x, lane = tid & 63, vt = tid >> 6;
  const int col = lane & 15, q = lane >> 4;

  bf16x8 bfr[2];
  const float* mr = MoS + (vt * 16 + col) * 64 + q * 8;
  bfr[0] = cvt8(*(const f32x4*)mr, *(const f32x4*)(mr + 4), 1.f);
  bfr[1] = cvt8(*(const f32x4*)(mr + 32), *(const f32x4*)(mr + 36), 1.f);
  const float cf = coS[vt * 16 + col];

  for (int t = 0; t < 16; t++) {
    const int b0 = (blockIdx.x * 16 + t) * 16;
    const unsigned short* xr = x16 + (long)(b0 + col) * 64 + q * 8;
    const bf16x8 a0 = *(const bf16x8*)xr;
    const bf16x8 a1 = *(const bf16x8*)(xr + 32);
    f32x4 acc = (f32x4){0.f, 0.f, 0.f, 0.f};
    acc = __builtin_amdgcn_mfma_f32_16x16x32_bf16(a0, bfr[0], acc, 0, 0, 0);
    acc = __builtin_amdgcn_mfma_f32_16x16x32_bf16(a1, bfr[1], acc, 0, 0, 0);
#pragma unroll
    for (int r = 0; r < 4; r++)
      out[(long)(b0 + q * 4 + r) * 64 + vt * 16 + col] = acc[r] + cf;
  }
}

extern "C" void kernel_launch(void* const* d_in, const int* in_sizes, int n_in,
                              void* d_out, int out_size, void* d_ws, size_t ws_size,
                              hipStream_t stream) {
  const float* x    = (const float*)d_in[0];
  const float* Win  = (const float*)d_in[1];
  const float* bin  = (const float*)d_in[2];
  const float* Wmid = (const float*)d_in[3];
  const float* bmid = (const float*)d_in[4];
  const float* Wout = (const float*)d_in[5];
  const float* bout = (const float*)d_in[6];
  float* out = (float*)d_out;
  float* ws  = (float*)d_ws;
  float* Gpart = out;   // 8.5 MB scratch inside d_out; fully overwritten by kApply
  unsigned short* x16 = (unsigned short*)(ws + OFF_X16);

  const size_t SMEM = (size_t)(8 * SLOT) * 2 + (396 + 8 + 64 * 68) * 4 + 64;  // ~92.8 KB
  hipFuncSetAttribute((const void*)kChainA,
                      hipFuncAttributeMaxDynamicSharedMemorySize, (int)SMEM);
  hipFuncSetAttribute((const void*)kChainB,
                      hipFuncAttributeMaxDynamicSharedMemorySize, (int)SMEM);

  kG   <<<512, 256, 0, stream>>>(x, Gpart, x16);
  kGred<<<65, 256, 0, stream>>>(Gpart, ws + OFF_G, ws + OFF_S);
  kChainA<<<16, 256, SMEM, stream>>>(Win, bin, Wmid, bmid, Wmid + 65536, bmid + 1024,
                                     ws + OFF_G, ws + OFF_S, ws + OFF_P2, ws + OFF_C2);
  kChainB<<<4, 256, SMEM, stream>>>(ws + OFF_P2, ws + OFF_C2,
                                    Wmid + 131072, bmid + 2048, Wout, bout,
                                    ws + OFF_G, ws + OFF_S, ws + OFF_P4, ws + OFF_C4);
  kNorm<<<1, 256, 0, stream>>>(ws + OFF_P4, ws + OFF_C4, ws + OFF_G, ws + OFF_S,
                               ws + OFF_MO, ws + OFF_CO);
  kApply<<<1024, 256, 0, stream>>>(x16, ws + OFF_MO, ws + OFF_CO, out);
}